// Round 2
// baseline (2164.724 us; speedup 1.0000x reference)
//
#include <hip/hip_runtime.h>
#include <hip/hip_bf16.h>

// ---------------- degree / norm kernels ----------------

__global__ void init_dinv_kernel(float* __restrict__ dinv, int n) {
    int i = blockIdx.x * blockDim.x + threadIdx.x;
    if (i < n) dinv[i] = 1.0f;   // self-loop contributes 1 to degree
}

__global__ void deg_kernel(const int* __restrict__ dst, float* __restrict__ dinv, int E) {
    int e = blockIdx.x * blockDim.x + threadIdx.x;
    if (e < E) atomicAdd(&dinv[dst[e]], 1.0f);
}

__global__ void rsqrt_kernel(float* __restrict__ dinv, int n) {
    int i = blockIdx.x * blockDim.x + threadIdx.x;
    if (i < n) dinv[i] = rsqrtf(dinv[i]);
}

// ---------------- GEMM1: h1 = relu(x) @ W1 ; agg1 = h1 * dinv^2 ----------------
// x: [n,128], W1: [128,128], h1/agg1: [n,128]

__global__ __launch_bounds__(256) void gemm1_kernel(
    const float* __restrict__ x, const float* __restrict__ W1,
    const float* __restrict__ dinv,
    float* __restrict__ h1, float* __restrict__ agg1, int n)
{
    __shared__ float Wl[128 * 128];      // 64 KB
    __shared__ float xl[8][128];         // 4 KB
    const int tid = threadIdx.x;

    // stage W1 into LDS (4096 float4, 16 per thread)
    {
        const float4* W4 = (const float4*)W1;
        float4* Wl4 = (float4*)Wl;
        #pragma unroll
        for (int i = 0; i < 16; ++i) Wl4[tid + i * 256] = W4[tid + i * 256];
    }
    __syncthreads();

    const int r  = tid >> 5;       // 0..7   row within pass
    const int j0 = (tid & 31) * 4; // output column group

    const int row0 = blockIdx.x * 64;
    for (int pass = 0; pass < 8; ++pass) {
        const int rbase = row0 + pass * 8;
        // load 8 rows of x with relu: 256 float4, 1 per thread
        {
            const int rr = tid >> 5;       // row 0..7
            const int c4 = tid & 31;       // float4 col
            const int grow = rbase + rr;
            float4 v = make_float4(0.f, 0.f, 0.f, 0.f);
            if (grow < n) v = *(const float4*)&x[(size_t)grow * 128 + c4 * 4];
            v.x = fmaxf(v.x, 0.f); v.y = fmaxf(v.y, 0.f);
            v.z = fmaxf(v.z, 0.f); v.w = fmaxf(v.w, 0.f);
            *(float4*)&xl[rr][c4 * 4] = v;
        }
        __syncthreads();

        float a0 = 0.f, a1 = 0.f, a2 = 0.f, a3 = 0.f;
        #pragma unroll 8
        for (int k = 0; k < 128; ++k) {
            const float xv = xl[r][k];
            const float4 w = *(const float4*)&Wl[k * 128 + j0];
            a0 = fmaf(xv, w.x, a0);
            a1 = fmaf(xv, w.y, a1);
            a2 = fmaf(xv, w.z, a2);
            a3 = fmaf(xv, w.w, a3);
        }
        const int grow = rbase + r;
        if (grow < n) {
            const float di = dinv[grow];
            const float s = di * di;
            *(float4*)&h1[(size_t)grow * 128 + j0]  = make_float4(a0, a1, a2, a3);
            *(float4*)&agg1[(size_t)grow * 128 + j0] = make_float4(a0 * s, a1 * s, a2 * s, a3 * s);
        }
        __syncthreads();
    }
}

// ---------------- GEMM2: h2 = relu(agg1 + b1) @ W2 ; agg2 = h2 * dinv^2 ----------------
// agg1: [n,128], W2: [128,64], h2: [n,64], agg2 -> d_out [n,64]

__global__ __launch_bounds__(256) void gemm2_kernel(
    const float* __restrict__ agg1, const float* __restrict__ b1,
    const float* __restrict__ W2, const float* __restrict__ dinv,
    float* __restrict__ h2, float* __restrict__ agg2, int n)
{
    __shared__ float Wl[128 * 64];   // 32 KB
    __shared__ float xl[16][128];    // 8 KB
    __shared__ float b1l[128];
    const int tid = threadIdx.x;

    // stage W2 (2048 float4, 8 per thread)
    {
        const float4* W4 = (const float4*)W2;
        float4* Wl4 = (float4*)Wl;
        #pragma unroll
        for (int i = 0; i < 8; ++i) Wl4[tid + i * 256] = W4[tid + i * 256];
    }
    if (tid < 128) b1l[tid] = b1[tid];
    __syncthreads();

    const int r  = tid >> 4;       // 0..15
    const int j0 = (tid & 15) * 4;

    const int row0 = blockIdx.x * 64;
    for (int pass = 0; pass < 4; ++pass) {
        const int rbase = row0 + pass * 16;
        // load 16 rows: 512 float4, 2 per thread; x1 = relu(agg1 + b1)
        #pragma unroll
        for (int t = 0; t < 2; ++t) {
            const int idx = tid + t * 256;
            const int rr = idx >> 5;
            const int c4 = idx & 31;
            const int grow = rbase + rr;
            float4 v = make_float4(0.f, 0.f, 0.f, 0.f);
            if (grow < n) v = *(const float4*)&agg1[(size_t)grow * 128 + c4 * 4];
            v.x = fmaxf(v.x + b1l[c4 * 4 + 0], 0.f);
            v.y = fmaxf(v.y + b1l[c4 * 4 + 1], 0.f);
            v.z = fmaxf(v.z + b1l[c4 * 4 + 2], 0.f);
            v.w = fmaxf(v.w + b1l[c4 * 4 + 3], 0.f);
            *(float4*)&xl[rr][c4 * 4] = v;
        }
        __syncthreads();

        float a0 = 0.f, a1 = 0.f, a2 = 0.f, a3 = 0.f;
        #pragma unroll 8
        for (int k = 0; k < 128; ++k) {
            const float xv = xl[r][k];
            const float4 w = *(const float4*)&Wl[k * 64 + j0];
            a0 = fmaf(xv, w.x, a0);
            a1 = fmaf(xv, w.y, a1);
            a2 = fmaf(xv, w.z, a2);
            a3 = fmaf(xv, w.w, a3);
        }
        const int grow = rbase + r;
        if (grow < n) {
            const float di = dinv[grow];
            const float s = di * di;
            *(float4*)&h2[(size_t)grow * 64 + j0]  = make_float4(a0, a1, a2, a3);
            *(float4*)&agg2[(size_t)grow * 64 + j0] = make_float4(a0 * s, a1 * s, a2 * s, a3 * s);
        }
        __syncthreads();
    }
}

// ---------------- edge scatter: agg[dst] += h[src] * dinv[src]*dinv[dst] ----------------

template <int FDIV4>
__global__ void scatter_kernel(const int* __restrict__ src, const int* __restrict__ dst,
                               const float* __restrict__ dinv, const float* __restrict__ h,
                               float* __restrict__ agg, int E)
{
    const int tid = blockIdx.x * blockDim.x + threadIdx.x;
    const int e = tid / FDIV4;
    const int c = tid % FDIV4;
    if (e >= E) return;
    const int s = src[e];
    const int d = dst[e];
    const float nrm = dinv[s] * dinv[d];
    const float4 v = *(const float4*)&h[(size_t)s * (FDIV4 * 4) + c * 4];
    float* out = &agg[(size_t)d * (FDIV4 * 4) + c * 4];
    atomicAdd(out + 0, v.x * nrm);
    atomicAdd(out + 1, v.y * nrm);
    atomicAdd(out + 2, v.z * nrm);
    atomicAdd(out + 3, v.w * nrm);
}

// ---------------- softmax over rows of 64 (+b2) ----------------

__global__ __launch_bounds__(256) void softmax_kernel(
    float* __restrict__ agg2, const float* __restrict__ b2, int n)
{
    const int gtid = blockIdx.x * blockDim.x + threadIdx.x;
    const int row = gtid >> 6;
    const int lane = threadIdx.x & 63;
    if (row >= n) return;
    float v = agg2[(size_t)row * 64 + lane] + b2[lane];
    float m = v;
    #pragma unroll
    for (int off = 32; off > 0; off >>= 1) m = fmaxf(m, __shfl_xor(m, off));
    const float ev = expf(v - m);
    float ssum = ev;
    #pragma unroll
    for (int off = 32; off > 0; off >>= 1) ssum += __shfl_xor(ssum, off);
    agg2[(size_t)row * 64 + lane] = ev / ssum;
}

// ---------------- launch ----------------

extern "C" void kernel_launch(void* const* d_in, const int* in_sizes, int n_in,
                              void* d_out, int out_size, void* d_ws, size_t ws_size,
                              hipStream_t stream)
{
    const float* x   = (const float*)d_in[0];
    const int*   ei  = (const int*)d_in[1];
    const float* W1  = (const float*)d_in[2];
    const float* b1  = (const float*)d_in[3];
    const float* W2  = (const float*)d_in[4];
    const float* b2  = (const float*)d_in[5];

    const int n = in_sizes[0] / 128;
    const int E = in_sizes[1] / 2;
    const int* src = ei;
    const int* dst = ei + E;

    float* ws   = (float*)d_ws;
    float* dinv = ws;                       // n
    float* h1   = dinv + n;                 // n*128  (n*4 bytes is 16B-aligned for n=50000)
    float* agg1 = h1 + (size_t)n * 128;     // n*128
    float* h2   = agg1 + (size_t)n * 128;   // n*64
    float* agg2 = (float*)d_out;            // n*64

    const int B = 256;

    init_dinv_kernel<<<(n + B - 1) / B, B, 0, stream>>>(dinv, n);
    deg_kernel<<<(E + B - 1) / B, B, 0, stream>>>(dst, dinv, E);
    rsqrt_kernel<<<(n + B - 1) / B, B, 0, stream>>>(dinv, n);

    const int gemm_blocks = (n + 63) / 64;
    gemm1_kernel<<<gemm_blocks, B, 0, stream>>>(x, W1, dinv, h1, agg1, n);

    {
        const long long total = (long long)E * 32;
        scatter_kernel<32><<<(int)((total + B - 1) / B), B, 0, stream>>>(src, dst, dinv, h1, agg1, E);
    }

    gemm2_kernel<<<gemm_blocks, B, 0, stream>>>(agg1, b1, W2, dinv, h2, agg2, n);

    {
        const long long total = (long long)E * 16;
        scatter_kernel<16><<<(int)((total + B - 1) / B), B, 0, stream>>>(src, dst, dinv, h2, agg2, E);
    }

    softmax_kernel<<<(int)(((long long)n * 64 + B - 1) / B), B, 0, stream>>>(agg2, b2, n);
}

// Round 4
// 356.174 us; speedup vs baseline: 6.0777x; 6.0777x over previous
//
#include <hip/hip_runtime.h>
#include <hip/hip_bf16.h>

// Pipeline (pull-mode GCN, no fp32 atomics):
//   CSR build by dst:  count -> scanA/scanB/scanC -> fill         (int atomics only)
//   z1   = Agg(relu(x))              [n,128]   gather1 (wave/node, relu on load)
//   x1   = relu(z1 @ W1 + b1)        [n,128]   gemm1 (in-place on z1 buffer)
//   h2   = x1 @ W2                   [n,64]    gemm2
//   out  = softmax(Agg(h2) + b2)     [n,64]    gather2+softmax fused
// Agg(v)[d] = v[d]*dinv[d]^2 + sum_{s in N(d)} v[s]*dinv[s]*dinv[d],  dinv = rsqrt(deg+1)

// ---------------- CSR build ----------------

__global__ void zero_count_kernel(int* __restrict__ count, int n) {
    int i = blockIdx.x * blockDim.x + threadIdx.x;
    if (i < n) count[i] = 0;
}

__global__ void count_kernel(const int* __restrict__ dst, int* __restrict__ count, int E) {
    int e = blockIdx.x * blockDim.x + threadIdx.x;
    if (e < E) atomicAdd(&count[dst[e]], 1);
}

#define SCAN_B 256

// per-block exclusive scan of count -> rowptr (local), block sums -> bsum
__global__ __launch_bounds__(SCAN_B) void scanA_kernel(
    const int* __restrict__ count, int* __restrict__ rowptr,
    int* __restrict__ bsum, int n)
{
    __shared__ int s[SCAN_B];
    const int tid = threadIdx.x;
    const int gid = blockIdx.x * SCAN_B + tid;
    const int v = (gid < n) ? count[gid] : 0;
    s[tid] = v;
    __syncthreads();
    for (int off = 1; off < SCAN_B; off <<= 1) {
        const int t = (tid >= off) ? s[tid - off] : 0;
        __syncthreads();
        s[tid] += t;
        __syncthreads();
    }
    if (gid < n) rowptr[gid] = s[tid] - v;            // exclusive
    if (tid == SCAN_B - 1) bsum[blockIdx.x] = s[tid]; // block total
}

// exclusive scan of block sums (nb <= 256 for n=50000 -> nb=196)
__global__ __launch_bounds__(SCAN_B) void scanB_kernel(
    const int* __restrict__ bsum, int* __restrict__ boff, int nb)
{
    __shared__ int s[SCAN_B];
    const int tid = threadIdx.x;
    const int v = (tid < nb) ? bsum[tid] : 0;
    s[tid] = v;
    __syncthreads();
    for (int off = 1; off < SCAN_B; off <<= 1) {
        const int t = (tid >= off) ? s[tid - off] : 0;
        __syncthreads();
        s[tid] += t;
        __syncthreads();
    }
    if (tid < nb) boff[tid] = s[tid] - v;
}

// rowptr += block offset; cursor = rowptr; dinv = rsqrt(count+1); rowptr[n]=E
__global__ void scanC_kernel(int* __restrict__ rowptr, const int* __restrict__ boff,
                             const int* __restrict__ count, int* __restrict__ cursor,
                             float* __restrict__ dinv, int n, int E)
{
    const int gid = blockIdx.x * blockDim.x + threadIdx.x;
    if (gid < n) {
        const int rp = rowptr[gid] + boff[gid >> 8];   // scanA block size = 256
        rowptr[gid] = rp;
        cursor[gid] = rp;
        dinv[gid] = rsqrtf((float)count[gid] + 1.0f);
    }
    if (gid == 0) rowptr[n] = E;
}

__global__ void fill_kernel(const int* __restrict__ src, const int* __restrict__ dst,
                            int* __restrict__ cursor, int* __restrict__ col, int E)
{
    const int e = blockIdx.x * blockDim.x + threadIdx.x;
    if (e < E) {
        const int pos = atomicAdd(&cursor[dst[e]], 1);
        col[pos] = src[e];
    }
}

// ---------------- gather1: z1[d] = Agg(relu(x))[d], F=128 (one wave/node, float2/lane) ----------------

__global__ __launch_bounds__(256) void gather1_kernel(
    const float* __restrict__ x, const int* __restrict__ rowptr,
    const int* __restrict__ col, const float* __restrict__ dinv,
    float* __restrict__ z1, int n)
{
    const int wid = blockIdx.x * 4 + (threadIdx.x >> 6);
    if (wid >= n) return;
    const int lane = threadIdx.x & 63;
    const float dd = dinv[wid];
    const size_t selfoff = (size_t)wid * 128 + lane * 2;
    const float2 sv = *(const float2*)&x[selfoff];
    float2 acc;
    acc.x = fmaxf(sv.x, 0.f) * dd * dd;
    acc.y = fmaxf(sv.y, 0.f) * dd * dd;
    const int jb = rowptr[wid];
    const int je = rowptr[wid + 1];
    for (int j = jb; j < je; ++j) {
        const int s = col[j];
        const float nrm = dinv[s] * dd;
        const float2 v = *(const float2*)&x[(size_t)s * 128 + lane * 2];
        acc.x = fmaf(fmaxf(v.x, 0.f), nrm, acc.x);
        acc.y = fmaf(fmaxf(v.y, 0.f), nrm, acc.y);
    }
    *(float2*)&z1[selfoff] = acc;
}

// ---------------- gemm1: x1 = relu(z1 @ W1 + b1), in-place (zin == x1out) ----------------

__global__ __launch_bounds__(256) void gemm1_kernel(
    const float* zin, const float* __restrict__ W1,
    const float* __restrict__ b1, float* x1out, int n)
{
    __shared__ float Wl[128 * 128];   // 64 KB
    __shared__ float xl[8][128];      // 4 KB
    __shared__ float b1l[128];
    const int tid = threadIdx.x;

    {
        const float4* W4 = (const float4*)W1;
        float4* Wl4 = (float4*)Wl;
        #pragma unroll
        for (int i = 0; i < 16; ++i) Wl4[tid + i * 256] = W4[tid + i * 256];
    }
    if (tid < 128) b1l[tid] = b1[tid];
    __syncthreads();

    const int r  = tid >> 5;        // 0..7
    const int j0 = (tid & 31) * 4;  // output col group

    const int row0 = blockIdx.x * 64;
    for (int pass = 0; pass < 8; ++pass) {
        const int rbase = row0 + pass * 8;
        {
            const int rr = tid >> 5;
            const int c4 = tid & 31;
            const int grow = rbase + rr;
            float4 v = make_float4(0.f, 0.f, 0.f, 0.f);
            if (grow < n) v = *(const float4*)&zin[(size_t)grow * 128 + c4 * 4];
            *(float4*)&xl[rr][c4 * 4] = v;
        }
        __syncthreads();

        float a0 = 0.f, a1 = 0.f, a2 = 0.f, a3 = 0.f;
        #pragma unroll 8
        for (int k = 0; k < 128; ++k) {
            const float xv = xl[r][k];
            const float4 w = *(const float4*)&Wl[k * 128 + j0];
            a0 = fmaf(xv, w.x, a0);
            a1 = fmaf(xv, w.y, a1);
            a2 = fmaf(xv, w.z, a2);
            a3 = fmaf(xv, w.w, a3);
        }
        const int grow = rbase + r;
        if (grow < n) {
            a0 = fmaxf(a0 + b1l[j0 + 0], 0.f);
            a1 = fmaxf(a1 + b1l[j0 + 1], 0.f);
            a2 = fmaxf(a2 + b1l[j0 + 2], 0.f);
            a3 = fmaxf(a3 + b1l[j0 + 3], 0.f);
            *(float4*)&x1out[(size_t)grow * 128 + j0] = make_float4(a0, a1, a2, a3);
        }
        __syncthreads();
    }
}

// ---------------- gemm2: h2 = x1 @ W2 ----------------

__global__ __launch_bounds__(256) void gemm2_kernel(
    const float* __restrict__ x1, const float* __restrict__ W2,
    float* __restrict__ h2, int n)
{
    __shared__ float Wl[128 * 64];   // 32 KB
    __shared__ float xl[16][128];    // 8 KB
    const int tid = threadIdx.x;

    {
        const float4* W4 = (const float4*)W2;
        float4* Wl4 = (float4*)Wl;
        #pragma unroll
        for (int i = 0; i < 8; ++i) Wl4[tid + i * 256] = W4[tid + i * 256];
    }
    __syncthreads();

    const int r  = tid >> 4;        // 0..15
    const int j0 = (tid & 15) * 4;

    const int row0 = blockIdx.x * 64;
    for (int pass = 0; pass < 4; ++pass) {
        const int rbase = row0 + pass * 16;
        #pragma unroll
        for (int t = 0; t < 2; ++t) {
            const int idx = tid + t * 256;
            const int rr = idx >> 5;
            const int c4 = idx & 31;
            const int grow = rbase + rr;
            float4 v = make_float4(0.f, 0.f, 0.f, 0.f);
            if (grow < n) v = *(const float4*)&x1[(size_t)grow * 128 + c4 * 4];
            *(float4*)&xl[rr][c4 * 4] = v;
        }
        __syncthreads();

        float a0 = 0.f, a1 = 0.f, a2 = 0.f, a3 = 0.f;
        #pragma unroll 8
        for (int k = 0; k < 128; ++k) {
            const float xv = xl[r][k];
            const float4 w = *(const float4*)&Wl[k * 64 + j0];
            a0 = fmaf(xv, w.x, a0);
            a1 = fmaf(xv, w.y, a1);
            a2 = fmaf(xv, w.z, a2);
            a3 = fmaf(xv, w.w, a3);
        }
        const int grow = rbase + r;
        if (grow < n) {
            *(float4*)&h2[(size_t)grow * 64 + j0] = make_float4(a0, a1, a2, a3);
        }
        __syncthreads();
    }
}

// ---------------- gather2 + bias + softmax: out[d] = softmax(Agg(h2)[d] + b2), F=64 ----------------

__global__ __launch_bounds__(256) void gather2_softmax_kernel(
    const float* __restrict__ h2, const int* __restrict__ rowptr,
    const int* __restrict__ col, const float* __restrict__ dinv,
    const float* __restrict__ b2, float* __restrict__ out, int n)
{
    const int wid = blockIdx.x * 4 + (threadIdx.x >> 6);
    if (wid >= n) return;
    const int lane = threadIdx.x & 63;
    const float dd = dinv[wid];
    float acc = h2[(size_t)wid * 64 + lane] * dd * dd;
    const int jb = rowptr[wid];
    const int je = rowptr[wid + 1];
    for (int j = jb; j < je; ++j) {
        const int s = col[j];
        acc = fmaf(h2[(size_t)s * 64 + lane], dinv[s] * dd, acc);
    }
    acc += b2[lane];

    float m = acc;
    #pragma unroll
    for (int off = 32; off > 0; off >>= 1) m = fmaxf(m, __shfl_xor(m, off));
    const float ev = expf(acc - m);
    float ssum = ev;
    #pragma unroll
    for (int off = 32; off > 0; off >>= 1) ssum += __shfl_xor(ssum, off);
    out[(size_t)wid * 64 + lane] = ev / ssum;
}

// ---------------- launch ----------------

extern "C" void kernel_launch(void* const* d_in, const int* in_sizes, int n_in,
                              void* d_out, int out_size, void* d_ws, size_t ws_size,
                              hipStream_t stream)
{
    const float* x   = (const float*)d_in[0];
    const int*   ei  = (const int*)d_in[1];
    const float* W1  = (const float*)d_in[2];
    const float* b1  = (const float*)d_in[3];
    const float* W2  = (const float*)d_in[4];
    const float* b2  = (const float*)d_in[5];

    const int n = in_sizes[0] / 128;
    const int E = in_sizes[1] / 2;
    const int* src = ei;
    const int* dst = ei + E;

    // workspace layout (~42.6 MB total, all 16B-aligned where vector-accessed)
    float* ws   = (float*)d_ws;
    float* dinv = ws;                          // n floats
    float* z1   = dinv + n;                    // n*128 floats (z1, then x1 in-place)
    float* h2   = z1 + (size_t)n * 128;        // n*64 floats
    int* count  = (int*)(h2 + (size_t)n * 64); // n
    int* rowptr = count + n;                   // n+1
    int* cursor = rowptr + (n + 1);            // n
    int* bsum   = cursor + n;                  // 256
    int* boff   = bsum + 256;                  // 256
    int* col    = boff + 256;                  // E

    const int B = 256;
    const int nb = (n + SCAN_B - 1) / SCAN_B;  // 196 for n=50000 (must be <= 256)

    // CSR build + dinv
    zero_count_kernel<<<(n + B - 1) / B, B, 0, stream>>>(count, n);
    count_kernel<<<(E + B - 1) / B, B, 0, stream>>>(dst, count, E);
    scanA_kernel<<<nb, SCAN_B, 0, stream>>>(count, rowptr, bsum, n);
    scanB_kernel<<<1, SCAN_B, 0, stream>>>(bsum, boff, nb);
    scanC_kernel<<<(n + B - 1) / B, B, 0, stream>>>(rowptr, boff, count, cursor, dinv, n, E);
    fill_kernel<<<(E + B - 1) / B, B, 0, stream>>>(src, dst, cursor, col, E);

    // layer 1: aggregate raw relu(x), then GEMM (+b1, relu) in-place
    const int gather_blocks = (n + 3) / 4;     // 4 waves (nodes) per block
    gather1_kernel<<<gather_blocks, B, 0, stream>>>(x, rowptr, col, dinv, z1, n);

    const int gemm_blocks = (n + 63) / 64;
    gemm1_kernel<<<gemm_blocks, B, 0, stream>>>(z1, W1, b1, z1, n);

    // layer 2: GEMM, then aggregate + bias + softmax fused
    gemm2_kernel<<<gemm_blocks, B, 0, stream>>>(z1, W2, h2, n);
    gather2_softmax_kernel<<<gather_blocks, B, 0, stream>>>(h2, rowptr, col, dinv, b2,
                                                            (float*)d_out, n);
}

// Round 5
// 281.029 us; speedup vs baseline: 7.7029x; 1.2674x over previous
//
#include <hip/hip_runtime.h>
#include <hip/hip_bf16.h>

// Pipeline (pull-mode GCN, no fp32 atomics):
//   CSR build by dst:  count -> scanA/scanB/scanC -> fill         (int atomics only)
//   z1   = Agg(relu(x))              [n,128]   gather1 (wave/node, relu on load, 4x unroll)
//   x1   = relu(z1 @ W1 + b1)        [n,128]   gemm1 (in-place on z1 buffer)
//   h2   = x1 @ W2                   [n,64]    gemm2
//   out  = softmax(Agg(h2) + b2)     [n,64]    gather2+softmax fused (4x unroll)
// Agg(v)[d] = v[d]*dinv[d]^2 + sum_{s in N(d)} v[s]*dinv[s]*dinv[d],  dinv = rsqrt(deg+1)

// ---------------- CSR build ----------------

__global__ void zero_count_kernel(int* __restrict__ count, int n) {
    int i = blockIdx.x * blockDim.x + threadIdx.x;
    if (i < n) count[i] = 0;
}

__global__ void count_kernel(const int* __restrict__ dst, int* __restrict__ count, int E) {
    int e = blockIdx.x * blockDim.x + threadIdx.x;
    if (e < E) atomicAdd(&count[dst[e]], 1);
}

#define SCAN_B 256

// per-block exclusive scan of count -> rowptr (local), block sums -> bsum
__global__ __launch_bounds__(SCAN_B) void scanA_kernel(
    const int* __restrict__ count, int* __restrict__ rowptr,
    int* __restrict__ bsum, int n)
{
    __shared__ int s[SCAN_B];
    const int tid = threadIdx.x;
    const int gid = blockIdx.x * SCAN_B + tid;
    const int v = (gid < n) ? count[gid] : 0;
    s[tid] = v;
    __syncthreads();
    for (int off = 1; off < SCAN_B; off <<= 1) {
        const int t = (tid >= off) ? s[tid - off] : 0;
        __syncthreads();
        s[tid] += t;
        __syncthreads();
    }
    if (gid < n) rowptr[gid] = s[tid] - v;            // exclusive
    if (tid == SCAN_B - 1) bsum[blockIdx.x] = s[tid]; // block total
}

// exclusive scan of block sums (nb <= 256 for n=50000 -> nb=196)
__global__ __launch_bounds__(SCAN_B) void scanB_kernel(
    const int* __restrict__ bsum, int* __restrict__ boff, int nb)
{
    __shared__ int s[SCAN_B];
    const int tid = threadIdx.x;
    const int v = (tid < nb) ? bsum[tid] : 0;
    s[tid] = v;
    __syncthreads();
    for (int off = 1; off < SCAN_B; off <<= 1) {
        const int t = (tid >= off) ? s[tid - off] : 0;
        __syncthreads();
        s[tid] += t;
        __syncthreads();
    }
    if (tid < nb) boff[tid] = s[tid] - v;
}

// rowptr += block offset; cursor = rowptr; dinv = rsqrt(count+1); rowptr[n]=E
__global__ void scanC_kernel(int* __restrict__ rowptr, const int* __restrict__ boff,
                             const int* __restrict__ count, int* __restrict__ cursor,
                             float* __restrict__ dinv, int n, int E)
{
    const int gid = blockIdx.x * blockDim.x + threadIdx.x;
    if (gid < n) {
        const int rp = rowptr[gid] + boff[gid >> 8];   // scanA block size = 256
        rowptr[gid] = rp;
        cursor[gid] = rp;
        dinv[gid] = rsqrtf((float)count[gid] + 1.0f);
    }
    if (gid == 0) rowptr[n] = E;
}

__global__ void fill_kernel(const int* __restrict__ src, const int* __restrict__ dst,
                            int* __restrict__ cursor, int* __restrict__ col, int E)
{
    const int e = blockIdx.x * blockDim.x + threadIdx.x;
    if (e < E) {
        const int pos = atomicAdd(&cursor[dst[e]], 1);
        col[pos] = src[e];
    }
}

// ---------------- gather1: z1[d] = Agg(relu(x))[d], F=128 (one wave/node, float2/lane) ----------------

__global__ __launch_bounds__(256) void gather1_kernel(
    const float* __restrict__ x, const int* __restrict__ rowptr,
    const int* __restrict__ col, const float* __restrict__ dinv,
    float* __restrict__ z1, int n)
{
    const int wid = blockIdx.x * 4 + (threadIdx.x >> 6);
    if (wid >= n) return;
    const int lane = threadIdx.x & 63;
    const float dd = dinv[wid];
    const size_t selfoff = (size_t)wid * 128 + lane * 2;
    const float2 sv = *(const float2*)&x[selfoff];
    float2 a0, a1, a2, a3;
    a0.x = fmaxf(sv.x, 0.f) * dd * dd;
    a0.y = fmaxf(sv.y, 0.f) * dd * dd;
    a1 = make_float2(0.f, 0.f);
    a2 = make_float2(0.f, 0.f);
    a3 = make_float2(0.f, 0.f);
    const int jb = rowptr[wid];
    const int je = rowptr[wid + 1];
    int j = jb;
    // 4-way unroll: 4 independent row gathers in flight per iteration
    for (; j + 3 < je; j += 4) {
        const int s0 = col[j + 0];
        const int s1 = col[j + 1];
        const int s2 = col[j + 2];
        const int s3 = col[j + 3];
        const float n0 = dinv[s0] * dd;
        const float n1 = dinv[s1] * dd;
        const float n2 = dinv[s2] * dd;
        const float n3 = dinv[s3] * dd;
        const float2 v0 = *(const float2*)&x[(size_t)s0 * 128 + lane * 2];
        const float2 v1 = *(const float2*)&x[(size_t)s1 * 128 + lane * 2];
        const float2 v2 = *(const float2*)&x[(size_t)s2 * 128 + lane * 2];
        const float2 v3 = *(const float2*)&x[(size_t)s3 * 128 + lane * 2];
        a0.x = fmaf(fmaxf(v0.x, 0.f), n0, a0.x);
        a0.y = fmaf(fmaxf(v0.y, 0.f), n0, a0.y);
        a1.x = fmaf(fmaxf(v1.x, 0.f), n1, a1.x);
        a1.y = fmaf(fmaxf(v1.y, 0.f), n1, a1.y);
        a2.x = fmaf(fmaxf(v2.x, 0.f), n2, a2.x);
        a2.y = fmaf(fmaxf(v2.y, 0.f), n2, a2.y);
        a3.x = fmaf(fmaxf(v3.x, 0.f), n3, a3.x);
        a3.y = fmaf(fmaxf(v3.y, 0.f), n3, a3.y);
    }
    for (; j < je; ++j) {
        const int s = col[j];
        const float nrm = dinv[s] * dd;
        const float2 v = *(const float2*)&x[(size_t)s * 128 + lane * 2];
        a0.x = fmaf(fmaxf(v.x, 0.f), nrm, a0.x);
        a0.y = fmaf(fmaxf(v.y, 0.f), nrm, a0.y);
    }
    float2 acc;
    acc.x = (a0.x + a1.x) + (a2.x + a3.x);
    acc.y = (a0.y + a1.y) + (a2.y + a3.y);
    *(float2*)&z1[selfoff] = acc;
}

// ---------------- gemm1: x1 = relu(z1 @ W1 + b1), in-place (zin == x1out) ----------------

__global__ __launch_bounds__(256) void gemm1_kernel(
    const float* zin, const float* __restrict__ W1,
    const float* __restrict__ b1, float* x1out, int n)
{
    __shared__ float Wl[128 * 128];   // 64 KB
    __shared__ float xl[8][128];      // 4 KB
    __shared__ float b1l[128];
    const int tid = threadIdx.x;

    {
        const float4* W4 = (const float4*)W1;
        float4* Wl4 = (float4*)Wl;
        #pragma unroll
        for (int i = 0; i < 16; ++i) Wl4[tid + i * 256] = W4[tid + i * 256];
    }
    if (tid < 128) b1l[tid] = b1[tid];
    __syncthreads();

    const int r  = tid >> 5;        // 0..7
    const int j0 = (tid & 31) * 4;  // output col group

    const int row0 = blockIdx.x * 64;
    for (int pass = 0; pass < 8; ++pass) {
        const int rbase = row0 + pass * 8;
        {
            const int rr = tid >> 5;
            const int c4 = tid & 31;
            const int grow = rbase + rr;
            float4 v = make_float4(0.f, 0.f, 0.f, 0.f);
            if (grow < n) v = *(const float4*)&zin[(size_t)grow * 128 + c4 * 4];
            *(float4*)&xl[rr][c4 * 4] = v;
        }
        __syncthreads();

        float a0 = 0.f, a1 = 0.f, a2 = 0.f, a3 = 0.f;
        #pragma unroll 8
        for (int k = 0; k < 128; ++k) {
            const float xv = xl[r][k];
            const float4 w = *(const float4*)&Wl[k * 128 + j0];
            a0 = fmaf(xv, w.x, a0);
            a1 = fmaf(xv, w.y, a1);
            a2 = fmaf(xv, w.z, a2);
            a3 = fmaf(xv, w.w, a3);
        }
        const int grow = rbase + r;
        if (grow < n) {
            a0 = fmaxf(a0 + b1l[j0 + 0], 0.f);
            a1 = fmaxf(a1 + b1l[j0 + 1], 0.f);
            a2 = fmaxf(a2 + b1l[j0 + 2], 0.f);
            a3 = fmaxf(a3 + b1l[j0 + 3], 0.f);
            *(float4*)&x1out[(size_t)grow * 128 + j0] = make_float4(a0, a1, a2, a3);
        }
        __syncthreads();
    }
}

// ---------------- gemm2: h2 = x1 @ W2 ----------------

__global__ __launch_bounds__(256) void gemm2_kernel(
    const float* __restrict__ x1, const float* __restrict__ W2,
    float* __restrict__ h2, int n)
{
    __shared__ float Wl[128 * 64];   // 32 KB
    __shared__ float xl[16][128];    // 8 KB
    const int tid = threadIdx.x;

    {
        const float4* W4 = (const float4*)W2;
        float4* Wl4 = (float4*)Wl;
        #pragma unroll
        for (int i = 0; i < 8; ++i) Wl4[tid + i * 256] = W4[tid + i * 256];
    }
    __syncthreads();

    const int r  = tid >> 4;        // 0..15
    const int j0 = (tid & 15) * 4;

    const int row0 = blockIdx.x * 64;
    for (int pass = 0; pass < 4; ++pass) {
        const int rbase = row0 + pass * 16;
        #pragma unroll
        for (int t = 0; t < 2; ++t) {
            const int idx = tid + t * 256;
            const int rr = idx >> 5;
            const int c4 = idx & 31;
            const int grow = rbase + rr;
            float4 v = make_float4(0.f, 0.f, 0.f, 0.f);
            if (grow < n) v = *(const float4*)&x1[(size_t)grow * 128 + c4 * 4];
            *(float4*)&xl[rr][c4 * 4] = v;
        }
        __syncthreads();

        float a0 = 0.f, a1 = 0.f, a2 = 0.f, a3 = 0.f;
        #pragma unroll 8
        for (int k = 0; k < 128; ++k) {
            const float xv = xl[r][k];
            const float4 w = *(const float4*)&Wl[k * 64 + j0];
            a0 = fmaf(xv, w.x, a0);
            a1 = fmaf(xv, w.y, a1);
            a2 = fmaf(xv, w.z, a2);
            a3 = fmaf(xv, w.w, a3);
        }
        const int grow = rbase + r;
        if (grow < n) {
            *(float4*)&h2[(size_t)grow * 64 + j0] = make_float4(a0, a1, a2, a3);
        }
        __syncthreads();
    }
}

// ---------------- gather2 + bias + softmax: out[d] = softmax(Agg(h2)[d] + b2), F=64 ----------------

__global__ __launch_bounds__(256) void gather2_softmax_kernel(
    const float* __restrict__ h2, const int* __restrict__ rowptr,
    const int* __restrict__ col, const float* __restrict__ dinv,
    const float* __restrict__ b2, float* __restrict__ out, int n)
{
    const int wid = blockIdx.x * 4 + (threadIdx.x >> 6);
    if (wid >= n) return;
    const int lane = threadIdx.x & 63;
    const float dd = dinv[wid];
    float a0 = h2[(size_t)wid * 64 + lane] * dd * dd;
    float a1 = 0.f, a2 = 0.f, a3 = 0.f;
    const int jb = rowptr[wid];
    const int je = rowptr[wid + 1];
    int j = jb;
    // 4-way unroll: 4 independent row gathers in flight per iteration
    for (; j + 3 < je; j += 4) {
        const int s0 = col[j + 0];
        const int s1 = col[j + 1];
        const int s2 = col[j + 2];
        const int s3 = col[j + 3];
        const float n0 = dinv[s0] * dd;
        const float n1 = dinv[s1] * dd;
        const float n2 = dinv[s2] * dd;
        const float n3 = dinv[s3] * dd;
        const float v0 = h2[(size_t)s0 * 64 + lane];
        const float v1 = h2[(size_t)s1 * 64 + lane];
        const float v2 = h2[(size_t)s2 * 64 + lane];
        const float v3 = h2[(size_t)s3 * 64 + lane];
        a0 = fmaf(v0, n0, a0);
        a1 = fmaf(v1, n1, a1);
        a2 = fmaf(v2, n2, a2);
        a3 = fmaf(v3, n3, a3);
    }
    for (; j < je; ++j) {
        const int s = col[j];
        a0 = fmaf(h2[(size_t)s * 64 + lane], dinv[s] * dd, a0);
    }
    float acc = (a0 + a1) + (a2 + a3);
    acc += b2[lane];

    float m = acc;
    #pragma unroll
    for (int off = 32; off > 0; off >>= 1) m = fmaxf(m, __shfl_xor(m, off));
    const float ev = expf(acc - m);
    float ssum = ev;
    #pragma unroll
    for (int off = 32; off > 0; off >>= 1) ssum += __shfl_xor(ssum, off);
    out[(size_t)wid * 64 + lane] = ev / ssum;
}

// ---------------- launch ----------------

extern "C" void kernel_launch(void* const* d_in, const int* in_sizes, int n_in,
                              void* d_out, int out_size, void* d_ws, size_t ws_size,
                              hipStream_t stream)
{
    const float* x   = (const float*)d_in[0];
    const int*   ei  = (const int*)d_in[1];
    const float* W1  = (const float*)d_in[2];
    const float* b1  = (const float*)d_in[3];
    const float* W2  = (const float*)d_in[4];
    const float* b2  = (const float*)d_in[5];

    const int n = in_sizes[0] / 128;
    const int E = in_sizes[1] / 2;
    const int* src = ei;
    const int* dst = ei + E;

    // workspace layout (~42.6 MB total, all 16B-aligned where vector-accessed)
    float* ws   = (float*)d_ws;
    float* dinv = ws;                          // n floats
    float* z1   = dinv + n;                    // n*128 floats (z1, then x1 in-place)
    float* h2   = z1 + (size_t)n * 128;        // n*64 floats
    int* count  = (int*)(h2 + (size_t)n * 64); // n
    int* rowptr = count + n;                   // n+1
    int* cursor = rowptr + (n + 1);            // n
    int* bsum   = cursor + n;                  // 256
    int* boff   = bsum + 256;                  // 256
    int* col    = boff + 256;                  // E

    const int B = 256;
    const int nb = (n + SCAN_B - 1) / SCAN_B;  // 196 for n=50000 (must be <= 256)

    // CSR build + dinv
    zero_count_kernel<<<(n + B - 1) / B, B, 0, stream>>>(count, n);
    count_kernel<<<(E + B - 1) / B, B, 0, stream>>>(dst, count, E);
    scanA_kernel<<<nb, SCAN_B, 0, stream>>>(count, rowptr, bsum, n);
    scanB_kernel<<<1, SCAN_B, 0, stream>>>(bsum, boff, nb);
    scanC_kernel<<<(n + B - 1) / B, B, 0, stream>>>(rowptr, boff, count, cursor, dinv, n, E);
    fill_kernel<<<(E + B - 1) / B, B, 0, stream>>>(src, dst, cursor, col, E);

    // layer 1: aggregate raw relu(x), then GEMM (+b1, relu) in-place
    const int gather_blocks = (n + 3) / 4;     // 4 waves (nodes) per block
    gather1_kernel<<<gather_blocks, B, 0, stream>>>(x, rowptr, col, dinv, z1, n);

    const int gemm_blocks = (n + 63) / 64;
    gemm1_kernel<<<gemm_blocks, B, 0, stream>>>(z1, W1, b1, z1, n);

    // layer 2: GEMM, then aggregate + bias + softmax fused
    gemm2_kernel<<<gemm_blocks, B, 0, stream>>>(z1, W2, h2, n);
    gather2_softmax_kernel<<<gather_blocks, B, 0, stream>>>(h2, rowptr, col, dinv, b2,
                                                            (float*)d_out, n);
}

// Round 6
// 270.837 us; speedup vs baseline: 7.9927x; 1.0376x over previous
//
#include <hip/hip_runtime.h>
#include <hip/hip_bf16.h>

// Pipeline (pull-mode GCN, no fp32 atomics):
//   CSR build by dst:  count -> scanA/scanB/scanC -> fill         (int atomics only)
//   z1   = Agg(relu(x))              [n,128]   gather1 (wave/node, relu on load, 8x unroll)
//   x1   = relu(z1 @ W1 + b1)        [n,128]   gemm1 (in-place, 2 rows x 4 cols / thread)
//   h2   = x1 @ W2                   [n,64]    gemm2 (2 rows x 4 cols / thread)
//   out  = softmax(Agg(h2) + b2)     [n,64]    gather2+softmax fused (8x unroll)
// Agg(v)[d] = v[d]*dinv[d]^2 + sum_{s in N(d)} v[s]*dinv[s]*dinv[d],  dinv = rsqrt(deg+1)

// ---------------- CSR build ----------------

__global__ void zero_count_kernel(int* __restrict__ count, int n) {
    int i = blockIdx.x * blockDim.x + threadIdx.x;
    if (i < n) count[i] = 0;
}

__global__ void count_kernel(const int* __restrict__ dst, int* __restrict__ count, int E) {
    int e = blockIdx.x * blockDim.x + threadIdx.x;
    if (e < E) atomicAdd(&count[dst[e]], 1);
}

#define SCAN_B 256

// per-block exclusive scan of count -> rowptr (local), block sums -> bsum
__global__ __launch_bounds__(SCAN_B) void scanA_kernel(
    const int* __restrict__ count, int* __restrict__ rowptr,
    int* __restrict__ bsum, int n)
{
    __shared__ int s[SCAN_B];
    const int tid = threadIdx.x;
    const int gid = blockIdx.x * SCAN_B + tid;
    const int v = (gid < n) ? count[gid] : 0;
    s[tid] = v;
    __syncthreads();
    for (int off = 1; off < SCAN_B; off <<= 1) {
        const int t = (tid >= off) ? s[tid - off] : 0;
        __syncthreads();
        s[tid] += t;
        __syncthreads();
    }
    if (gid < n) rowptr[gid] = s[tid] - v;            // exclusive
    if (tid == SCAN_B - 1) bsum[blockIdx.x] = s[tid]; // block total
}

// exclusive scan of block sums (nb <= 256 for n=50000 -> nb=196)
__global__ __launch_bounds__(SCAN_B) void scanB_kernel(
    const int* __restrict__ bsum, int* __restrict__ boff, int nb)
{
    __shared__ int s[SCAN_B];
    const int tid = threadIdx.x;
    const int v = (tid < nb) ? bsum[tid] : 0;
    s[tid] = v;
    __syncthreads();
    for (int off = 1; off < SCAN_B; off <<= 1) {
        const int t = (tid >= off) ? s[tid - off] : 0;
        __syncthreads();
        s[tid] += t;
        __syncthreads();
    }
    if (tid < nb) boff[tid] = s[tid] - v;
}

// rowptr += block offset; cursor = rowptr; dinv = rsqrt(count+1); rowptr[n]=E
__global__ void scanC_kernel(int* __restrict__ rowptr, const int* __restrict__ boff,
                             const int* __restrict__ count, int* __restrict__ cursor,
                             float* __restrict__ dinv, int n, int E)
{
    const int gid = blockIdx.x * blockDim.x + threadIdx.x;
    if (gid < n) {
        const int rp = rowptr[gid] + boff[gid >> 8];   // scanA block size = 256
        rowptr[gid] = rp;
        cursor[gid] = rp;
        dinv[gid] = rsqrtf((float)count[gid] + 1.0f);
    }
    if (gid == 0) rowptr[n] = E;
}

__global__ void fill_kernel(const int* __restrict__ src, const int* __restrict__ dst,
                            int* __restrict__ cursor, int* __restrict__ col, int E)
{
    const int e = blockIdx.x * blockDim.x + threadIdx.x;
    if (e < E) {
        const int pos = atomicAdd(&cursor[dst[e]], 1);
        col[pos] = src[e];
    }
}

// ---------------- gather1: z1[d] = Agg(relu(x))[d], F=128 (one wave/node, float2/lane, 8x unroll) ----------------

__global__ __launch_bounds__(256) void gather1_kernel(
    const float* __restrict__ x, const int* __restrict__ rowptr,
    const int* __restrict__ col, const float* __restrict__ dinv,
    float* __restrict__ z1, int n)
{
    const int wid = blockIdx.x * 4 + (threadIdx.x >> 6);
    if (wid >= n) return;
    const int lane = threadIdx.x & 63;
    const float dd = dinv[wid];
    const size_t selfoff = (size_t)wid * 128 + lane * 2;
    const float2 sv = *(const float2*)&x[selfoff];
    float2 a0, a1, a2, a3;
    a0.x = fmaxf(sv.x, 0.f) * dd * dd;
    a0.y = fmaxf(sv.y, 0.f) * dd * dd;
    a1 = make_float2(0.f, 0.f);
    a2 = make_float2(0.f, 0.f);
    a3 = make_float2(0.f, 0.f);
    const int jb = rowptr[wid];
    const int je = rowptr[wid + 1];
    int j = jb;
    // 8-way unroll: 8 independent row gathers in flight per iteration
    for (; j + 7 < je; j += 8) {
        const int s0 = col[j + 0];
        const int s1 = col[j + 1];
        const int s2 = col[j + 2];
        const int s3 = col[j + 3];
        const int s4 = col[j + 4];
        const int s5 = col[j + 5];
        const int s6 = col[j + 6];
        const int s7 = col[j + 7];
        const float n0 = dinv[s0] * dd;
        const float n1 = dinv[s1] * dd;
        const float n2 = dinv[s2] * dd;
        const float n3 = dinv[s3] * dd;
        const float n4 = dinv[s4] * dd;
        const float n5 = dinv[s5] * dd;
        const float n6 = dinv[s6] * dd;
        const float n7 = dinv[s7] * dd;
        const float2 v0 = *(const float2*)&x[(size_t)s0 * 128 + lane * 2];
        const float2 v1 = *(const float2*)&x[(size_t)s1 * 128 + lane * 2];
        const float2 v2 = *(const float2*)&x[(size_t)s2 * 128 + lane * 2];
        const float2 v3 = *(const float2*)&x[(size_t)s3 * 128 + lane * 2];
        const float2 v4 = *(const float2*)&x[(size_t)s4 * 128 + lane * 2];
        const float2 v5 = *(const float2*)&x[(size_t)s5 * 128 + lane * 2];
        const float2 v6 = *(const float2*)&x[(size_t)s6 * 128 + lane * 2];
        const float2 v7 = *(const float2*)&x[(size_t)s7 * 128 + lane * 2];
        a0.x = fmaf(fmaxf(v0.x, 0.f), n0, a0.x);
        a0.y = fmaf(fmaxf(v0.y, 0.f), n0, a0.y);
        a1.x = fmaf(fmaxf(v1.x, 0.f), n1, a1.x);
        a1.y = fmaf(fmaxf(v1.y, 0.f), n1, a1.y);
        a2.x = fmaf(fmaxf(v2.x, 0.f), n2, a2.x);
        a2.y = fmaf(fmaxf(v2.y, 0.f), n2, a2.y);
        a3.x = fmaf(fmaxf(v3.x, 0.f), n3, a3.x);
        a3.y = fmaf(fmaxf(v3.y, 0.f), n3, a3.y);
        a0.x = fmaf(fmaxf(v4.x, 0.f), n4, a0.x);
        a0.y = fmaf(fmaxf(v4.y, 0.f), n4, a0.y);
        a1.x = fmaf(fmaxf(v5.x, 0.f), n5, a1.x);
        a1.y = fmaf(fmaxf(v5.y, 0.f), n5, a1.y);
        a2.x = fmaf(fmaxf(v6.x, 0.f), n6, a2.x);
        a2.y = fmaf(fmaxf(v6.y, 0.f), n6, a2.y);
        a3.x = fmaf(fmaxf(v7.x, 0.f), n7, a3.x);
        a3.y = fmaf(fmaxf(v7.y, 0.f), n7, a3.y);
    }
    for (; j < je; ++j) {
        const int s = col[j];
        const float nrm = dinv[s] * dd;
        const float2 v = *(const float2*)&x[(size_t)s * 128 + lane * 2];
        a0.x = fmaf(fmaxf(v.x, 0.f), nrm, a0.x);
        a0.y = fmaf(fmaxf(v.y, 0.f), nrm, a0.y);
    }
    float2 acc;
    acc.x = (a0.x + a1.x) + (a2.x + a3.x);
    acc.y = (a0.y + a1.y) + (a2.y + a3.y);
    *(float2*)&z1[selfoff] = acc;
}

// ---------------- gemm1: x1 = relu(z1 @ W1 + b1), in-place; 2 rows x 4 cols / thread ----------------

__global__ __launch_bounds__(256) void gemm1_kernel(
    const float* zin, const float* __restrict__ W1,
    const float* __restrict__ b1, float* x1out, int n)
{
    __shared__ float Wl[128 * 128];   // 64 KB
    __shared__ float xl[16][128];     // 8 KB
    __shared__ float b1l[128];
    const int tid = threadIdx.x;

    {
        const float4* W4 = (const float4*)W1;
        float4* Wl4 = (float4*)Wl;
        #pragma unroll
        for (int i = 0; i < 16; ++i) Wl4[tid + i * 256] = W4[tid + i * 256];
    }
    if (tid < 128) b1l[tid] = b1[tid];
    __syncthreads();

    const int colg = tid & 31;        // 32 col groups x 4 cols = 128 cols
    const int j0   = colg * 4;
    const int r0   = (tid >> 5) * 2;  // 8 row groups x 2 rows = 16 rows/pass

    const int row0 = blockIdx.x * 64;
    for (int pass = 0; pass < 4; ++pass) {
        const int rbase = row0 + pass * 16;
        // load 16 rows into LDS: 512 float4, 2 per thread
        #pragma unroll
        for (int t = 0; t < 2; ++t) {
            const int idx = tid + t * 256;
            const int rr = idx >> 5;
            const int c4 = idx & 31;
            const int grow = rbase + rr;
            float4 v = make_float4(0.f, 0.f, 0.f, 0.f);
            if (grow < n) v = *(const float4*)&zin[(size_t)grow * 128 + c4 * 4];
            *(float4*)&xl[rr][c4 * 4] = v;
        }
        __syncthreads();

        float c00 = 0.f, c01 = 0.f, c02 = 0.f, c03 = 0.f;
        float c10 = 0.f, c11 = 0.f, c12 = 0.f, c13 = 0.f;
        #pragma unroll 8
        for (int k = 0; k < 128; ++k) {
            const float x0 = xl[r0 + 0][k];
            const float x1 = xl[r0 + 1][k];
            const float4 w = *(const float4*)&Wl[k * 128 + j0];
            c00 = fmaf(x0, w.x, c00); c01 = fmaf(x0, w.y, c01);
            c02 = fmaf(x0, w.z, c02); c03 = fmaf(x0, w.w, c03);
            c10 = fmaf(x1, w.x, c10); c11 = fmaf(x1, w.y, c11);
            c12 = fmaf(x1, w.z, c12); c13 = fmaf(x1, w.w, c13);
        }
        const float bb0 = b1l[j0 + 0], bb1 = b1l[j0 + 1];
        const float bb2 = b1l[j0 + 2], bb3 = b1l[j0 + 3];
        const int g0 = rbase + r0;
        const int g1 = g0 + 1;
        if (g0 < n) {
            *(float4*)&x1out[(size_t)g0 * 128 + j0] = make_float4(
                fmaxf(c00 + bb0, 0.f), fmaxf(c01 + bb1, 0.f),
                fmaxf(c02 + bb2, 0.f), fmaxf(c03 + bb3, 0.f));
        }
        if (g1 < n) {
            *(float4*)&x1out[(size_t)g1 * 128 + j0] = make_float4(
                fmaxf(c10 + bb0, 0.f), fmaxf(c11 + bb1, 0.f),
                fmaxf(c12 + bb2, 0.f), fmaxf(c13 + bb3, 0.f));
        }
        __syncthreads();
    }
}

// ---------------- gemm2: h2 = x1 @ W2; 2 rows x 4 cols / thread ----------------

__global__ __launch_bounds__(256) void gemm2_kernel(
    const float* __restrict__ x1, const float* __restrict__ W2,
    float* __restrict__ h2, int n)
{
    __shared__ float Wl[128 * 64];   // 32 KB
    __shared__ float xl[32][128];    // 16 KB
    const int tid = threadIdx.x;

    {
        const float4* W4 = (const float4*)W2;
        float4* Wl4 = (float4*)Wl;
        #pragma unroll
        for (int i = 0; i < 8; ++i) Wl4[tid + i * 256] = W4[tid + i * 256];
    }
    __syncthreads();

    const int colg = tid & 15;        // 16 col groups x 4 cols = 64 cols
    const int j0   = colg * 4;
    const int r0   = (tid >> 4) * 2;  // 16 row groups x 2 rows = 32 rows/pass

    const int row0 = blockIdx.x * 64;
    for (int pass = 0; pass < 2; ++pass) {
        const int rbase = row0 + pass * 32;
        // load 32 rows into LDS: 1024 float4, 4 per thread
        #pragma unroll
        for (int t = 0; t < 4; ++t) {
            const int idx = tid + t * 256;
            const int rr = idx >> 5;
            const int c4 = idx & 31;
            const int grow = rbase + rr;
            float4 v = make_float4(0.f, 0.f, 0.f, 0.f);
            if (grow < n) v = *(const float4*)&x1[(size_t)grow * 128 + c4 * 4];
            *(float4*)&xl[rr][c4 * 4] = v;
        }
        __syncthreads();

        float c00 = 0.f, c01 = 0.f, c02 = 0.f, c03 = 0.f;
        float c10 = 0.f, c11 = 0.f, c12 = 0.f, c13 = 0.f;
        #pragma unroll 8
        for (int k = 0; k < 128; ++k) {
            const float x0 = xl[r0 + 0][k];
            const float x1v = xl[r0 + 1][k];
            const float4 w = *(const float4*)&Wl[k * 64 + j0];
            c00 = fmaf(x0, w.x, c00);  c01 = fmaf(x0, w.y, c01);
            c02 = fmaf(x0, w.z, c02);  c03 = fmaf(x0, w.w, c03);
            c10 = fmaf(x1v, w.x, c10); c11 = fmaf(x1v, w.y, c11);
            c12 = fmaf(x1v, w.z, c12); c13 = fmaf(x1v, w.w, c13);
        }
        const int g0 = rbase + r0;
        const int g1 = g0 + 1;
        if (g0 < n) *(float4*)&h2[(size_t)g0 * 64 + j0] = make_float4(c00, c01, c02, c03);
        if (g1 < n) *(float4*)&h2[(size_t)g1 * 64 + j0] = make_float4(c10, c11, c12, c13);
        __syncthreads();
    }
}

// ---------------- gather2 + bias + softmax: out[d] = softmax(Agg(h2)[d] + b2), F=64, 8x unroll ----------------

__global__ __launch_bounds__(256) void gather2_softmax_kernel(
    const float* __restrict__ h2, const int* __restrict__ rowptr,
    const int* __restrict__ col, const float* __restrict__ dinv,
    const float* __restrict__ b2, float* __restrict__ out, int n)
{
    const int wid = blockIdx.x * 4 + (threadIdx.x >> 6);
    if (wid >= n) return;
    const int lane = threadIdx.x & 63;
    const float bias = b2[lane];
    const float dd = dinv[wid];
    float a0 = h2[(size_t)wid * 64 + lane] * dd * dd;
    float a1 = 0.f, a2 = 0.f, a3 = 0.f;
    const int jb = rowptr[wid];
    const int je = rowptr[wid + 1];
    int j = jb;
    // 8-way unroll: 8 independent row gathers in flight per iteration
    for (; j + 7 < je; j += 8) {
        const int s0 = col[j + 0];
        const int s1 = col[j + 1];
        const int s2 = col[j + 2];
        const int s3 = col[j + 3];
        const int s4 = col[j + 4];
        const int s5 = col[j + 5];
        const int s6 = col[j + 6];
        const int s7 = col[j + 7];
        const float n0 = dinv[s0] * dd;
        const float n1 = dinv[s1] * dd;
        const float n2 = dinv[s2] * dd;
        const float n3 = dinv[s3] * dd;
        const float n4 = dinv[s4] * dd;
        const float n5 = dinv[s5] * dd;
        const float n6 = dinv[s6] * dd;
        const float n7 = dinv[s7] * dd;
        const float v0 = h2[(size_t)s0 * 64 + lane];
        const float v1 = h2[(size_t)s1 * 64 + lane];
        const float v2 = h2[(size_t)s2 * 64 + lane];
        const float v3 = h2[(size_t)s3 * 64 + lane];
        const float v4 = h2[(size_t)s4 * 64 + lane];
        const float v5 = h2[(size_t)s5 * 64 + lane];
        const float v6 = h2[(size_t)s6 * 64 + lane];
        const float v7 = h2[(size_t)s7 * 64 + lane];
        a0 = fmaf(v0, n0, a0);
        a1 = fmaf(v1, n1, a1);
        a2 = fmaf(v2, n2, a2);
        a3 = fmaf(v3, n3, a3);
        a0 = fmaf(v4, n4, a0);
        a1 = fmaf(v5, n5, a1);
        a2 = fmaf(v6, n6, a2);
        a3 = fmaf(v7, n7, a3);
    }
    for (; j < je; ++j) {
        const int s = col[j];
        a0 = fmaf(h2[(size_t)s * 64 + lane], dinv[s] * dd, a0);
    }
    float acc = (a0 + a1) + (a2 + a3);
    acc += bias;

    float m = acc;
    #pragma unroll
    for (int off = 32; off > 0; off >>= 1) m = fmaxf(m, __shfl_xor(m, off));
    const float ev = expf(acc - m);
    float ssum = ev;
    #pragma unroll
    for (int off = 32; off > 0; off >>= 1) ssum += __shfl_xor(ssum, off);
    out[(size_t)wid * 64 + lane] = ev / ssum;
}

// ---------------- launch ----------------

extern "C" void kernel_launch(void* const* d_in, const int* in_sizes, int n_in,
                              void* d_out, int out_size, void* d_ws, size_t ws_size,
                              hipStream_t stream)
{
    const float* x   = (const float*)d_in[0];
    const int*   ei  = (const int*)d_in[1];
    const float* W1  = (const float*)d_in[2];
    const float* b1  = (const float*)d_in[3];
    const float* W2  = (const float*)d_in[4];
    const float* b2  = (const float*)d_in[5];

    const int n = in_sizes[0] / 128;
    const int E = in_sizes[1] / 2;
    const int* src = ei;
    const int* dst = ei + E;

    // workspace layout (~42.6 MB total, all 16B-aligned where vector-accessed)
    float* ws   = (float*)d_ws;
    float* dinv = ws;                          // n floats
    float* z1   = dinv + n;                    // n*128 floats (z1, then x1 in-place)
    float* h2   = z1 + (size_t)n * 128;        // n*64 floats
    int* count  = (int*)(h2 + (size_t)n * 64); // n
    int* rowptr = count + n;                   // n+1
    int* cursor = rowptr + (n + 1);            // n
    int* bsum   = cursor + n;                  // 256
    int* boff   = bsum + 256;                  // 256
    int* col    = boff + 256;                  // E

    const int B = 256;
    const int nb = (n + SCAN_B - 1) / SCAN_B;  // 196 for n=50000 (must be <= 256)

    // CSR build + dinv
    zero_count_kernel<<<(n + B - 1) / B, B, 0, stream>>>(count, n);
    count_kernel<<<(E + B - 1) / B, B, 0, stream>>>(dst, count, E);
    scanA_kernel<<<nb, SCAN_B, 0, stream>>>(count, rowptr, bsum, n);
    scanB_kernel<<<1, SCAN_B, 0, stream>>>(bsum, boff, nb);
    scanC_kernel<<<(n + B - 1) / B, B, 0, stream>>>(rowptr, boff, count, cursor, dinv, n, E);
    fill_kernel<<<(E + B - 1) / B, B, 0, stream>>>(src, dst, cursor, col, E);

    // layer 1: aggregate raw relu(x), then GEMM (+b1, relu) in-place
    const int gather_blocks = (n + 3) / 4;     // 4 waves (nodes) per block
    gather1_kernel<<<gather_blocks, B, 0, stream>>>(x, rowptr, col, dinv, z1, n);

    const int gemm_blocks = (n + 63) / 64;
    gemm1_kernel<<<gemm_blocks, B, 0, stream>>>(z1, W1, b1, z1, n);

    // layer 2: GEMM, then aggregate + bias + softmax fused
    gemm2_kernel<<<gemm_blocks, B, 0, stream>>>(z1, W2, h2, n);
    gather2_softmax_kernel<<<gather_blocks, B, 0, stream>>>(h2, rowptr, col, dinv, b2,
                                                            (float*)d_out, n);
}

// Round 7
// 269.224 us; speedup vs baseline: 8.0406x; 1.0060x over previous
//
#include <hip/hip_runtime.h>
#include <hip/hip_bf16.h>

// Pipeline (pull-mode GCN, no fp32 atomics):
//   CSR build by dst:  count -> scanA/scanB/scanC -> fill         (int atomics only)
//   z1   = Agg(relu(x))              [n,128]   gather1 (wave/node, relu on load, 8x unroll)
//   x1   = relu(z1 @ W1 + b1)        [n,128]   gemm1 (512 thr, 4x4/thread, single sync)
//   h2   = x1 @ W2                   [n,64]    gemm2 (512 thr, 4x4/thread, single sync)
//   out  = softmax(Agg(h2) + b2)     [n,64]    gather2+softmax fused (8x unroll)
// Agg(v)[d] = v[d]*dinv[d]^2 + sum_{s in N(d)} v[s]*dinv[s]*dinv[d],  dinv = rsqrt(deg+1)

// ---------------- CSR build ----------------

__global__ void zero_count_kernel(int* __restrict__ count, int n) {
    int i = blockIdx.x * blockDim.x + threadIdx.x;
    if (i < n) count[i] = 0;
}

__global__ void count_kernel(const int* __restrict__ dst, int* __restrict__ count, int E) {
    int e = blockIdx.x * blockDim.x + threadIdx.x;
    if (e < E) atomicAdd(&count[dst[e]], 1);
}

#define SCAN_B 256

// per-block exclusive scan of count -> rowptr (local), block sums -> bsum
__global__ __launch_bounds__(SCAN_B) void scanA_kernel(
    const int* __restrict__ count, int* __restrict__ rowptr,
    int* __restrict__ bsum, int n)
{
    __shared__ int s[SCAN_B];
    const int tid = threadIdx.x;
    const int gid = blockIdx.x * SCAN_B + tid;
    const int v = (gid < n) ? count[gid] : 0;
    s[tid] = v;
    __syncthreads();
    for (int off = 1; off < SCAN_B; off <<= 1) {
        const int t = (tid >= off) ? s[tid - off] : 0;
        __syncthreads();
        s[tid] += t;
        __syncthreads();
    }
    if (gid < n) rowptr[gid] = s[tid] - v;            // exclusive
    if (tid == SCAN_B - 1) bsum[blockIdx.x] = s[tid]; // block total
}

// exclusive scan of block sums (nb <= 256 for n=50000 -> nb=196)
__global__ __launch_bounds__(SCAN_B) void scanB_kernel(
    const int* __restrict__ bsum, int* __restrict__ boff, int nb)
{
    __shared__ int s[SCAN_B];
    const int tid = threadIdx.x;
    const int v = (tid < nb) ? bsum[tid] : 0;
    s[tid] = v;
    __syncthreads();
    for (int off = 1; off < SCAN_B; off <<= 1) {
        const int t = (tid >= off) ? s[tid - off] : 0;
        __syncthreads();
        s[tid] += t;
        __syncthreads();
    }
    if (tid < nb) boff[tid] = s[tid] - v;
}

// rowptr += block offset; cursor = rowptr; dinv = rsqrt(count+1); rowptr[n]=E
__global__ void scanC_kernel(int* __restrict__ rowptr, const int* __restrict__ boff,
                             const int* __restrict__ count, int* __restrict__ cursor,
                             float* __restrict__ dinv, int n, int E)
{
    const int gid = blockIdx.x * blockDim.x + threadIdx.x;
    if (gid < n) {
        const int rp = rowptr[gid] + boff[gid >> 8];   // scanA block size = 256
        rowptr[gid] = rp;
        cursor[gid] = rp;
        dinv[gid] = rsqrtf((float)count[gid] + 1.0f);
    }
    if (gid == 0) rowptr[n] = E;
}

__global__ void fill_kernel(const int* __restrict__ src, const int* __restrict__ dst,
                            int* __restrict__ cursor, int* __restrict__ col, int E)
{
    const int e = blockIdx.x * blockDim.x + threadIdx.x;
    if (e < E) {
        const int pos = atomicAdd(&cursor[dst[e]], 1);
        col[pos] = src[e];
    }
}

// ---------------- gather1: z1[d] = Agg(relu(x))[d], F=128 (one wave/node, float2/lane, 8x unroll) ----------------

__global__ __launch_bounds__(256) void gather1_kernel(
    const float* __restrict__ x, const int* __restrict__ rowptr,
    const int* __restrict__ col, const float* __restrict__ dinv,
    float* __restrict__ z1, int n)
{
    const int wid = blockIdx.x * 4 + (threadIdx.x >> 6);
    if (wid >= n) return;
    const int lane = threadIdx.x & 63;
    const float dd = dinv[wid];
    const size_t selfoff = (size_t)wid * 128 + lane * 2;
    const float2 sv = *(const float2*)&x[selfoff];
    float2 a0, a1, a2, a3;
    a0.x = fmaxf(sv.x, 0.f) * dd * dd;
    a0.y = fmaxf(sv.y, 0.f) * dd * dd;
    a1 = make_float2(0.f, 0.f);
    a2 = make_float2(0.f, 0.f);
    a3 = make_float2(0.f, 0.f);
    const int jb = rowptr[wid];
    const int je = rowptr[wid + 1];
    int j = jb;
    // 8-way unroll: 8 independent row gathers in flight per iteration
    for (; j + 7 < je; j += 8) {
        const int s0 = col[j + 0];
        const int s1 = col[j + 1];
        const int s2 = col[j + 2];
        const int s3 = col[j + 3];
        const int s4 = col[j + 4];
        const int s5 = col[j + 5];
        const int s6 = col[j + 6];
        const int s7 = col[j + 7];
        const float n0 = dinv[s0] * dd;
        const float n1 = dinv[s1] * dd;
        const float n2 = dinv[s2] * dd;
        const float n3 = dinv[s3] * dd;
        const float n4 = dinv[s4] * dd;
        const float n5 = dinv[s5] * dd;
        const float n6 = dinv[s6] * dd;
        const float n7 = dinv[s7] * dd;
        const float2 v0 = *(const float2*)&x[(size_t)s0 * 128 + lane * 2];
        const float2 v1 = *(const float2*)&x[(size_t)s1 * 128 + lane * 2];
        const float2 v2 = *(const float2*)&x[(size_t)s2 * 128 + lane * 2];
        const float2 v3 = *(const float2*)&x[(size_t)s3 * 128 + lane * 2];
        const float2 v4 = *(const float2*)&x[(size_t)s4 * 128 + lane * 2];
        const float2 v5 = *(const float2*)&x[(size_t)s5 * 128 + lane * 2];
        const float2 v6 = *(const float2*)&x[(size_t)s6 * 128 + lane * 2];
        const float2 v7 = *(const float2*)&x[(size_t)s7 * 128 + lane * 2];
        a0.x = fmaf(fmaxf(v0.x, 0.f), n0, a0.x);
        a0.y = fmaf(fmaxf(v0.y, 0.f), n0, a0.y);
        a1.x = fmaf(fmaxf(v1.x, 0.f), n1, a1.x);
        a1.y = fmaf(fmaxf(v1.y, 0.f), n1, a1.y);
        a2.x = fmaf(fmaxf(v2.x, 0.f), n2, a2.x);
        a2.y = fmaf(fmaxf(v2.y, 0.f), n2, a2.y);
        a3.x = fmaf(fmaxf(v3.x, 0.f), n3, a3.x);
        a3.y = fmaf(fmaxf(v3.y, 0.f), n3, a3.y);
        a0.x = fmaf(fmaxf(v4.x, 0.f), n4, a0.x);
        a0.y = fmaf(fmaxf(v4.y, 0.f), n4, a0.y);
        a1.x = fmaf(fmaxf(v5.x, 0.f), n5, a1.x);
        a1.y = fmaf(fmaxf(v5.y, 0.f), n5, a1.y);
        a2.x = fmaf(fmaxf(v6.x, 0.f), n6, a2.x);
        a2.y = fmaf(fmaxf(v6.y, 0.f), n6, a2.y);
        a3.x = fmaf(fmaxf(v7.x, 0.f), n7, a3.x);
        a3.y = fmaf(fmaxf(v7.y, 0.f), n7, a3.y);
    }
    for (; j < je; ++j) {
        const int s = col[j];
        const float nrm = dinv[s] * dd;
        const float2 v = *(const float2*)&x[(size_t)s * 128 + lane * 2];
        a0.x = fmaf(fmaxf(v.x, 0.f), nrm, a0.x);
        a0.y = fmaf(fmaxf(v.y, 0.f), nrm, a0.y);
    }
    float2 acc;
    acc.x = (a0.x + a1.x) + (a2.x + a3.x);
    acc.y = (a0.y + a1.y) + (a2.y + a3.y);
    *(float2*)&z1[selfoff] = acc;
}

// ---------------- gemm1: x1 = relu(z1 @ W1 + b1), in-place; 512 thr, 64-row block, 4x4/thread ----------------
// LDS: W1 64KB + xl[64][128] 32KB + b1 = 96.5KB -> 1 block/CU (8 waves resident).
// Single __syncthreads; K-order per output unchanged (bit-identical GEMM results).

__global__ __launch_bounds__(512) void gemm1_kernel(
    const float* zin, const float* __restrict__ W1,
    const float* __restrict__ b1, float* x1out, int n)
{
    __shared__ float Wl[128 * 128];   // 64 KB
    __shared__ float xl[64][128];     // 32 KB
    __shared__ float b1l[128];
    const int tid = threadIdx.x;

    // stage W1: 4096 float4, 8 per thread
    {
        const float4* W4 = (const float4*)W1;
        float4* Wl4 = (float4*)Wl;
        #pragma unroll
        for (int i = 0; i < 8; ++i) Wl4[tid + i * 512] = W4[tid + i * 512];
    }
    if (tid < 128) b1l[tid] = b1[tid];

    const int row0 = blockIdx.x * 64;
    // stage 64 rows of z1: 2048 float4, 4 per thread
    #pragma unroll
    for (int t = 0; t < 4; ++t) {
        const int idx = tid + t * 512;
        const int rr = idx >> 5;
        const int c4 = idx & 31;
        const int grow = row0 + rr;
        float4 v = make_float4(0.f, 0.f, 0.f, 0.f);
        if (grow < n) v = *(const float4*)&zin[(size_t)grow * 128 + c4 * 4];
        *(float4*)&xl[rr][c4 * 4] = v;
    }
    __syncthreads();

    const int colg = tid & 31;        // 32 col groups x 4 cols = 128 cols
    const int j0   = colg * 4;
    const int r0   = (tid >> 5) * 4;  // 16 row groups x 4 rows = 64 rows

    float c00 = 0.f, c01 = 0.f, c02 = 0.f, c03 = 0.f;
    float c10 = 0.f, c11 = 0.f, c12 = 0.f, c13 = 0.f;
    float c20 = 0.f, c21 = 0.f, c22 = 0.f, c23 = 0.f;
    float c30 = 0.f, c31 = 0.f, c32 = 0.f, c33 = 0.f;
    #pragma unroll 8
    for (int k = 0; k < 128; ++k) {
        const float4 w = *(const float4*)&Wl[k * 128 + j0];
        const float x0 = xl[r0 + 0][k];
        const float x1 = xl[r0 + 1][k];
        const float x2 = xl[r0 + 2][k];
        const float x3 = xl[r0 + 3][k];
        c00 = fmaf(x0, w.x, c00); c01 = fmaf(x0, w.y, c01);
        c02 = fmaf(x0, w.z, c02); c03 = fmaf(x0, w.w, c03);
        c10 = fmaf(x1, w.x, c10); c11 = fmaf(x1, w.y, c11);
        c12 = fmaf(x1, w.z, c12); c13 = fmaf(x1, w.w, c13);
        c20 = fmaf(x2, w.x, c20); c21 = fmaf(x2, w.y, c21);
        c22 = fmaf(x2, w.z, c22); c23 = fmaf(x2, w.w, c23);
        c30 = fmaf(x3, w.x, c30); c31 = fmaf(x3, w.y, c31);
        c32 = fmaf(x3, w.z, c32); c33 = fmaf(x3, w.w, c33);
    }
    const float bb0 = b1l[j0 + 0], bb1 = b1l[j0 + 1];
    const float bb2 = b1l[j0 + 2], bb3 = b1l[j0 + 3];
    const int g0 = row0 + r0;
    if (g0 + 0 < n) *(float4*)&x1out[(size_t)(g0 + 0) * 128 + j0] = make_float4(
        fmaxf(c00 + bb0, 0.f), fmaxf(c01 + bb1, 0.f), fmaxf(c02 + bb2, 0.f), fmaxf(c03 + bb3, 0.f));
    if (g0 + 1 < n) *(float4*)&x1out[(size_t)(g0 + 1) * 128 + j0] = make_float4(
        fmaxf(c10 + bb0, 0.f), fmaxf(c11 + bb1, 0.f), fmaxf(c12 + bb2, 0.f), fmaxf(c13 + bb3, 0.f));
    if (g0 + 2 < n) *(float4*)&x1out[(size_t)(g0 + 2) * 128 + j0] = make_float4(
        fmaxf(c20 + bb0, 0.f), fmaxf(c21 + bb1, 0.f), fmaxf(c22 + bb2, 0.f), fmaxf(c23 + bb3, 0.f));
    if (g0 + 3 < n) *(float4*)&x1out[(size_t)(g0 + 3) * 128 + j0] = make_float4(
        fmaxf(c30 + bb0, 0.f), fmaxf(c31 + bb1, 0.f), fmaxf(c32 + bb2, 0.f), fmaxf(c33 + bb3, 0.f));
}

// ---------------- gemm2: h2 = x1 @ W2; 512 thr, 128-row block, 4x4/thread ----------------
// LDS: W2 32KB + xl[128][132] 66KB (pad +4 -> row-reads conflict-free) = 98KB -> 1 block/CU.

#define XL2_LD 132

__global__ __launch_bounds__(512) void gemm2_kernel(
    const float* __restrict__ x1, const float* __restrict__ W2,
    float* __restrict__ h2, int n)
{
    __shared__ float Wl[128 * 64];        // 32 KB
    __shared__ float xl[128 * XL2_LD];    // 66 KB (padded rows, 528B each, 16B-aligned)
    const int tid = threadIdx.x;

    // stage W2: 2048 float4, 4 per thread
    {
        const float4* W4 = (const float4*)W2;
        float4* Wl4 = (float4*)Wl;
        #pragma unroll
        for (int i = 0; i < 4; ++i) Wl4[tid + i * 512] = W4[tid + i * 512];
    }

    const int row0 = blockIdx.x * 128;
    // stage 128 rows of x1: 4096 float4, 8 per thread
    #pragma unroll
    for (int t = 0; t < 8; ++t) {
        const int idx = tid + t * 512;
        const int rr = idx >> 5;
        const int c4 = idx & 31;
        const int grow = row0 + rr;
        float4 v = make_float4(0.f, 0.f, 0.f, 0.f);
        if (grow < n) v = *(const float4*)&x1[(size_t)grow * 128 + c4 * 4];
        *(float4*)&xl[rr * XL2_LD + c4 * 4] = v;
    }
    __syncthreads();

    const int colg = tid & 15;        // 16 col groups x 4 cols = 64 cols
    const int j0   = colg * 4;
    const int r0   = (tid >> 4) * 4;  // 32 row groups x 4 rows = 128 rows

    float c00 = 0.f, c01 = 0.f, c02 = 0.f, c03 = 0.f;
    float c10 = 0.f, c11 = 0.f, c12 = 0.f, c13 = 0.f;
    float c20 = 0.f, c21 = 0.f, c22 = 0.f, c23 = 0.f;
    float c30 = 0.f, c31 = 0.f, c32 = 0.f, c33 = 0.f;
    #pragma unroll 8
    for (int k = 0; k < 128; ++k) {
        const float4 w = *(const float4*)&Wl[k * 64 + j0];
        const float x0 = xl[(r0 + 0) * XL2_LD + k];
        const float x1v = xl[(r0 + 1) * XL2_LD + k];
        const float x2 = xl[(r0 + 2) * XL2_LD + k];
        const float x3 = xl[(r0 + 3) * XL2_LD + k];
        c00 = fmaf(x0, w.x, c00);  c01 = fmaf(x0, w.y, c01);
        c02 = fmaf(x0, w.z, c02);  c03 = fmaf(x0, w.w, c03);
        c10 = fmaf(x1v, w.x, c10); c11 = fmaf(x1v, w.y, c11);
        c12 = fmaf(x1v, w.z, c12); c13 = fmaf(x1v, w.w, c13);
        c20 = fmaf(x2, w.x, c20);  c21 = fmaf(x2, w.y, c21);
        c22 = fmaf(x2, w.z, c22);  c23 = fmaf(x2, w.w, c23);
        c30 = fmaf(x3, w.x, c30);  c31 = fmaf(x3, w.y, c31);
        c32 = fmaf(x3, w.z, c32);  c33 = fmaf(x3, w.w, c33);
    }
    const int g0 = row0 + r0;
    if (g0 + 0 < n) *(float4*)&h2[(size_t)(g0 + 0) * 64 + j0] = make_float4(c00, c01, c02, c03);
    if (g0 + 1 < n) *(float4*)&h2[(size_t)(g0 + 1) * 64 + j0] = make_float4(c10, c11, c12, c13);
    if (g0 + 2 < n) *(float4*)&h2[(size_t)(g0 + 2) * 64 + j0] = make_float4(c20, c21, c22, c23);
    if (g0 + 3 < n) *(float4*)&h2[(size_t)(g0 + 3) * 64 + j0] = make_float4(c30, c31, c32, c33);
}

// ---------------- gather2 + bias + softmax: out[d] = softmax(Agg(h2)[d] + b2), F=64, 8x unroll ----------------

__global__ __launch_bounds__(256) void gather2_softmax_kernel(
    const float* __restrict__ h2, const int* __restrict__ rowptr,
    const int* __restrict__ col, const float* __restrict__ dinv,
    const float* __restrict__ b2, float* __restrict__ out, int n)
{
    const int wid = blockIdx.x * 4 + (threadIdx.x >> 6);
    if (wid >= n) return;
    const int lane = threadIdx.x & 63;
    const float bias = b2[lane];
    const float dd = dinv[wid];
    float a0 = h2[(size_t)wid * 64 + lane] * dd * dd;
    float a1 = 0.f, a2 = 0.f, a3 = 0.f;
    const int jb = rowptr[wid];
    const int je = rowptr[wid + 1];
    int j = jb;
    // 8-way unroll: 8 independent row gathers in flight per iteration
    for (; j + 7 < je; j += 8) {
        const int s0 = col[j + 0];
        const int s1 = col[j + 1];
        const int s2 = col[j + 2];
        const int s3 = col[j + 3];
        const int s4 = col[j + 4];
        const int s5 = col[j + 5];
        const int s6 = col[j + 6];
        const int s7 = col[j + 7];
        const float n0 = dinv[s0] * dd;
        const float n1 = dinv[s1] * dd;
        const float n2 = dinv[s2] * dd;
        const float n3 = dinv[s3] * dd;
        const float n4 = dinv[s4] * dd;
        const float n5 = dinv[s5] * dd;
        const float n6 = dinv[s6] * dd;
        const float n7 = dinv[s7] * dd;
        const float v0 = h2[(size_t)s0 * 64 + lane];
        const float v1 = h2[(size_t)s1 * 64 + lane];
        const float v2 = h2[(size_t)s2 * 64 + lane];
        const float v3 = h2[(size_t)s3 * 64 + lane];
        const float v4 = h2[(size_t)s4 * 64 + lane];
        const float v5 = h2[(size_t)s5 * 64 + lane];
        const float v6 = h2[(size_t)s6 * 64 + lane];
        const float v7 = h2[(size_t)s7 * 64 + lane];
        a0 = fmaf(v0, n0, a0);
        a1 = fmaf(v1, n1, a1);
        a2 = fmaf(v2, n2, a2);
        a3 = fmaf(v3, n3, a3);
        a0 = fmaf(v4, n4, a0);
        a1 = fmaf(v5, n5, a1);
        a2 = fmaf(v6, n6, a2);
        a3 = fmaf(v7, n7, a3);
    }
    for (; j < je; ++j) {
        const int s = col[j];
        a0 = fmaf(h2[(size_t)s * 64 + lane], dinv[s] * dd, a0);
    }
    float acc = (a0 + a1) + (a2 + a3);
    acc += bias;

    float m = acc;
    #pragma unroll
    for (int off = 32; off > 0; off >>= 1) m = fmaxf(m, __shfl_xor(m, off));
    const float ev = expf(acc - m);
    float ssum = ev;
    #pragma unroll
    for (int off = 32; off > 0; off >>= 1) ssum += __shfl_xor(ssum, off);
    out[(size_t)wid * 64 + lane] = ev / ssum;
}

// ---------------- launch ----------------

extern "C" void kernel_launch(void* const* d_in, const int* in_sizes, int n_in,
                              void* d_out, int out_size, void* d_ws, size_t ws_size,
                              hipStream_t stream)
{
    const float* x   = (const float*)d_in[0];
    const int*   ei  = (const int*)d_in[1];
    const float* W1  = (const float*)d_in[2];
    const float* b1  = (const float*)d_in[3];
    const float* W2  = (const float*)d_in[4];
    const float* b2  = (const float*)d_in[5];

    const int n = in_sizes[0] / 128;
    const int E = in_sizes[1] / 2;
    const int* src = ei;
    const int* dst = ei + E;

    // workspace layout (~42.6 MB total, all 16B-aligned where vector-accessed)
    float* ws   = (float*)d_ws;
    float* dinv = ws;                          // n floats
    float* z1   = dinv + n;                    // n*128 floats (z1, then x1 in-place)
    float* h2   = z1 + (size_t)n * 128;        // n*64 floats
    int* count  = (int*)(h2 + (size_t)n * 64); // n
    int* rowptr = count + n;                   // n+1
    int* cursor = rowptr + (n + 1);            // n
    int* bsum   = cursor + n;                  // 256
    int* boff   = bsum + 256;                  // 256
    int* col    = boff + 256;                  // E

    const int B = 256;
    const int nb = (n + SCAN_B - 1) / SCAN_B;  // 196 for n=50000 (must be <= 256)

    // CSR build + dinv
    zero_count_kernel<<<(n + B - 1) / B, B, 0, stream>>>(count, n);
    count_kernel<<<(E + B - 1) / B, B, 0, stream>>>(dst, count, E);
    scanA_kernel<<<nb, SCAN_B, 0, stream>>>(count, rowptr, bsum, n);
    scanB_kernel<<<1, SCAN_B, 0, stream>>>(bsum, boff, nb);
    scanC_kernel<<<(n + B - 1) / B, B, 0, stream>>>(rowptr, boff, count, cursor, dinv, n, E);
    fill_kernel<<<(E + B - 1) / B, B, 0, stream>>>(src, dst, cursor, col, E);

    // layer 1: aggregate raw relu(x), then GEMM (+b1, relu) in-place
    const int gather_blocks = (n + 3) / 4;     // 4 waves (nodes) per block
    gather1_kernel<<<gather_blocks, B, 0, stream>>>(x, rowptr, col, dinv, z1, n);

    gemm1_kernel<<<(n + 63) / 64, 512, 0, stream>>>(z1, W1, b1, z1, n);

    // layer 2: GEMM, then aggregate + bias + softmax fused
    gemm2_kernel<<<(n + 127) / 128, 512, 0, stream>>>(z1, W2, h2, n);
    gather2_softmax_kernel<<<gather_blocks, B, 0, stream>>>(h2, rowptr, col, dinv, b2,
                                                            (float*)d_out, n);
}

// Round 8
// 248.767 us; speedup vs baseline: 8.7018x; 1.0822x over previous
//
#include <hip/hip_runtime.h>
#include <hip/hip_bf16.h>
#include <hip/hip_fp16.h>

// Pipeline (pull-mode GCN, no fp32 atomics, fp16-staged gather operands):
//   x_h  = (half)relu(x)             [n,128]   relu_half
//   CSR build by dst:  count -> scanA/scanB/scanC -> fill         (int atomics only)
//   z1   = Agg(x_h)                  [n,128]   gather1 (wave/node, 8x unroll, fp32 accum)
//   x1   = relu(z1 @ W1 + b1)        [n,128]   gemm1 (512 thr, 4x4/thread, single sync)
//   h2h  = (half)(x1 @ W2)           [n,64]    gemm2 (512 thr, 4x4/thread, fp16 store)
//   out  = softmax(Agg(h2h) + b2)    [n,64]    gather2+softmax fused (8x unroll, fp32 accum)
// Agg(v)[d] = v[d]*dinv[d]^2 + sum_{s in N(d)} v[s]*dinv[s]*dinv[d],  dinv = rsqrt(deg+1)

// ---------------- x -> relu -> fp16 ----------------

__global__ __launch_bounds__(256) void relu_half_kernel(
    const float* __restrict__ x, __half* __restrict__ xh, int total8)
{
    const int i = blockIdx.x * blockDim.x + threadIdx.x;
    if (i >= total8) return;
    const float4 v0 = *(const float4*)&x[(size_t)i * 8];
    const float4 v1 = *(const float4*)&x[(size_t)i * 8 + 4];
    union { __half2 h[4]; float4 f; } u;
    u.h[0] = __floats2half2_rn(fmaxf(v0.x, 0.f), fmaxf(v0.y, 0.f));
    u.h[1] = __floats2half2_rn(fmaxf(v0.z, 0.f), fmaxf(v0.w, 0.f));
    u.h[2] = __floats2half2_rn(fmaxf(v1.x, 0.f), fmaxf(v1.y, 0.f));
    u.h[3] = __floats2half2_rn(fmaxf(v1.z, 0.f), fmaxf(v1.w, 0.f));
    *(float4*)&xh[(size_t)i * 8] = u.f;
}

// ---------------- CSR build ----------------

__global__ void zero_count_kernel(int* __restrict__ count, int n) {
    int i = blockIdx.x * blockDim.x + threadIdx.x;
    if (i < n) count[i] = 0;
}

__global__ void count_kernel(const int* __restrict__ dst, int* __restrict__ count, int E) {
    int e = blockIdx.x * blockDim.x + threadIdx.x;
    if (e < E) atomicAdd(&count[dst[e]], 1);
}

#define SCAN_B 256

// per-block exclusive scan of count -> rowptr (local), block sums -> bsum
__global__ __launch_bounds__(SCAN_B) void scanA_kernel(
    const int* __restrict__ count, int* __restrict__ rowptr,
    int* __restrict__ bsum, int n)
{
    __shared__ int s[SCAN_B];
    const int tid = threadIdx.x;
    const int gid = blockIdx.x * SCAN_B + tid;
    const int v = (gid < n) ? count[gid] : 0;
    s[tid] = v;
    __syncthreads();
    for (int off = 1; off < SCAN_B; off <<= 1) {
        const int t = (tid >= off) ? s[tid - off] : 0;
        __syncthreads();
        s[tid] += t;
        __syncthreads();
    }
    if (gid < n) rowptr[gid] = s[tid] - v;            // exclusive
    if (tid == SCAN_B - 1) bsum[blockIdx.x] = s[tid]; // block total
}

// exclusive scan of block sums (nb <= 256 for n=50000 -> nb=196)
__global__ __launch_bounds__(SCAN_B) void scanB_kernel(
    const int* __restrict__ bsum, int* __restrict__ boff, int nb)
{
    __shared__ int s[SCAN_B];
    const int tid = threadIdx.x;
    const int v = (tid < nb) ? bsum[tid] : 0;
    s[tid] = v;
    __syncthreads();
    for (int off = 1; off < SCAN_B; off <<= 1) {
        const int t = (tid >= off) ? s[tid - off] : 0;
        __syncthreads();
        s[tid] += t;
        __syncthreads();
    }
    if (tid < nb) boff[tid] = s[tid] - v;
}

// rowptr += block offset; cursor = rowptr; dinv = rsqrt(count+1); rowptr[n]=E
__global__ void scanC_kernel(int* __restrict__ rowptr, const int* __restrict__ boff,
                             const int* __restrict__ count, int* __restrict__ cursor,
                             float* __restrict__ dinv, int n, int E)
{
    const int gid = blockIdx.x * blockDim.x + threadIdx.x;
    if (gid < n) {
        const int rp = rowptr[gid] + boff[gid >> 8];   // scanA block size = 256
        rowptr[gid] = rp;
        cursor[gid] = rp;
        dinv[gid] = rsqrtf((float)count[gid] + 1.0f);
    }
    if (gid == 0) rowptr[n] = E;
}

__global__ void fill_kernel(const int* __restrict__ src, const int* __restrict__ dst,
                            int* __restrict__ cursor, int* __restrict__ col, int E)
{
    const int e = blockIdx.x * blockDim.x + threadIdx.x;
    if (e < E) {
        const int pos = atomicAdd(&cursor[dst[e]], 1);
        col[pos] = src[e];
    }
}

// ---------------- gather1: z1[d] = Agg(x_h)[d], F=128 (one wave/node, half2/lane, 8x unroll) ----------------

__global__ __launch_bounds__(256) void gather1_kernel(
    const __half* __restrict__ xh, const int* __restrict__ rowptr,
    const int* __restrict__ col, const float* __restrict__ dinv,
    float* __restrict__ z1, int n)
{
    const int wid = blockIdx.x * 4 + (threadIdx.x >> 6);
    if (wid >= n) return;
    const int lane = threadIdx.x & 63;
    const float dd = dinv[wid];
    const size_t selfoff = (size_t)wid * 128 + lane * 2;
    const float2 sv = __half22float2(*(const __half2*)&xh[selfoff]);
    float2 a0, a1, a2, a3;
    a0.x = sv.x * dd * dd;
    a0.y = sv.y * dd * dd;
    a1 = make_float2(0.f, 0.f);
    a2 = make_float2(0.f, 0.f);
    a3 = make_float2(0.f, 0.f);
    const int jb = rowptr[wid];
    const int je = rowptr[wid + 1];
    int j = jb;
    // 8-way unroll: 8 independent row gathers in flight per iteration
    for (; j + 7 < je; j += 8) {
        const int s0 = col[j + 0];
        const int s1 = col[j + 1];
        const int s2 = col[j + 2];
        const int s3 = col[j + 3];
        const int s4 = col[j + 4];
        const int s5 = col[j + 5];
        const int s6 = col[j + 6];
        const int s7 = col[j + 7];
        const float n0 = dinv[s0] * dd;
        const float n1 = dinv[s1] * dd;
        const float n2 = dinv[s2] * dd;
        const float n3 = dinv[s3] * dd;
        const float n4 = dinv[s4] * dd;
        const float n5 = dinv[s5] * dd;
        const float n6 = dinv[s6] * dd;
        const float n7 = dinv[s7] * dd;
        const float2 v0 = __half22float2(*(const __half2*)&xh[(size_t)s0 * 128 + lane * 2]);
        const float2 v1 = __half22float2(*(const __half2*)&xh[(size_t)s1 * 128 + lane * 2]);
        const float2 v2 = __half22float2(*(const __half2*)&xh[(size_t)s2 * 128 + lane * 2]);
        const float2 v3 = __half22float2(*(const __half2*)&xh[(size_t)s3 * 128 + lane * 2]);
        const float2 v4 = __half22float2(*(const __half2*)&xh[(size_t)s4 * 128 + lane * 2]);
        const float2 v5 = __half22float2(*(const __half2*)&xh[(size_t)s5 * 128 + lane * 2]);
        const float2 v6 = __half22float2(*(const __half2*)&xh[(size_t)s6 * 128 + lane * 2]);
        const float2 v7 = __half22float2(*(const __half2*)&xh[(size_t)s7 * 128 + lane * 2]);
        a0.x = fmaf(v0.x, n0, a0.x);
        a0.y = fmaf(v0.y, n0, a0.y);
        a1.x = fmaf(v1.x, n1, a1.x);
        a1.y = fmaf(v1.y, n1, a1.y);
        a2.x = fmaf(v2.x, n2, a2.x);
        a2.y = fmaf(v2.y, n2, a2.y);
        a3.x = fmaf(v3.x, n3, a3.x);
        a3.y = fmaf(v3.y, n3, a3.y);
        a0.x = fmaf(v4.x, n4, a0.x);
        a0.y = fmaf(v4.y, n4, a0.y);
        a1.x = fmaf(v5.x, n5, a1.x);
        a1.y = fmaf(v5.y, n5, a1.y);
        a2.x = fmaf(v6.x, n6, a2.x);
        a2.y = fmaf(v6.y, n6, a2.y);
        a3.x = fmaf(v7.x, n7, a3.x);
        a3.y = fmaf(v7.y, n7, a3.y);
    }
    for (; j < je; ++j) {
        const int s = col[j];
        const float nrm = dinv[s] * dd;
        const float2 v = __half22float2(*(const __half2*)&xh[(size_t)s * 128 + lane * 2]);
        a0.x = fmaf(v.x, nrm, a0.x);
        a0.y = fmaf(v.y, nrm, a0.y);
    }
    float2 acc;
    acc.x = (a0.x + a1.x) + (a2.x + a3.x);
    acc.y = (a0.y + a1.y) + (a2.y + a3.y);
    *(float2*)&z1[selfoff] = acc;
}

// ---------------- gemm1: x1 = relu(z1 @ W1 + b1), in-place; 512 thr, 64-row block, 4x4/thread ----------------
// LDS: W1 64KB + xl[64][128] 32KB + b1 = 96.5KB -> 1 block/CU (8 waves resident).

__global__ __launch_bounds__(512) void gemm1_kernel(
    const float* zin, const float* __restrict__ W1,
    const float* __restrict__ b1, float* x1out, int n)
{
    __shared__ float Wl[128 * 128];   // 64 KB
    __shared__ float xl[64][128];     // 32 KB
    __shared__ float b1l[128];
    const int tid = threadIdx.x;

    // stage W1: 4096 float4, 8 per thread
    {
        const float4* W4 = (const float4*)W1;
        float4* Wl4 = (float4*)Wl;
        #pragma unroll
        for (int i = 0; i < 8; ++i) Wl4[tid + i * 512] = W4[tid + i * 512];
    }
    if (tid < 128) b1l[tid] = b1[tid];

    const int row0 = blockIdx.x * 64;
    // stage 64 rows of z1: 2048 float4, 4 per thread
    #pragma unroll
    for (int t = 0; t < 4; ++t) {
        const int idx = tid + t * 512;
        const int rr = idx >> 5;
        const int c4 = idx & 31;
        const int grow = row0 + rr;
        float4 v = make_float4(0.f, 0.f, 0.f, 0.f);
        if (grow < n) v = *(const float4*)&zin[(size_t)grow * 128 + c4 * 4];
        *(float4*)&xl[rr][c4 * 4] = v;
    }
    __syncthreads();

    const int colg = tid & 31;        // 32 col groups x 4 cols = 128 cols
    const int j0   = colg * 4;
    const int r0   = (tid >> 5) * 4;  // 16 row groups x 4 rows = 64 rows

    float c00 = 0.f, c01 = 0.f, c02 = 0.f, c03 = 0.f;
    float c10 = 0.f, c11 = 0.f, c12 = 0.f, c13 = 0.f;
    float c20 = 0.f, c21 = 0.f, c22 = 0.f, c23 = 0.f;
    float c30 = 0.f, c31 = 0.f, c32 = 0.f, c33 = 0.f;
    #pragma unroll 8
    for (int k = 0; k < 128; ++k) {
        const float4 w = *(const float4*)&Wl[k * 128 + j0];
        const float x0 = xl[r0 + 0][k];
        const float x1 = xl[r0 + 1][k];
        const float x2 = xl[r0 + 2][k];
        const float x3 = xl[r0 + 3][k];
        c00 = fmaf(x0, w.x, c00); c01 = fmaf(x0, w.y, c01);
        c02 = fmaf(x0, w.z, c02); c03 = fmaf(x0, w.w, c03);
        c10 = fmaf(x1, w.x, c10); c11 = fmaf(x1, w.y, c11);
        c12 = fmaf(x1, w.z, c12); c13 = fmaf(x1, w.w, c13);
        c20 = fmaf(x2, w.x, c20); c21 = fmaf(x2, w.y, c21);
        c22 = fmaf(x2, w.z, c22); c23 = fmaf(x2, w.w, c23);
        c30 = fmaf(x3, w.x, c30); c31 = fmaf(x3, w.y, c31);
        c32 = fmaf(x3, w.z, c32); c33 = fmaf(x3, w.w, c33);
    }
    const float bb0 = b1l[j0 + 0], bb1 = b1l[j0 + 1];
    const float bb2 = b1l[j0 + 2], bb3 = b1l[j0 + 3];
    const int g0 = row0 + r0;
    if (g0 + 0 < n) *(float4*)&x1out[(size_t)(g0 + 0) * 128 + j0] = make_float4(
        fmaxf(c00 + bb0, 0.f), fmaxf(c01 + bb1, 0.f), fmaxf(c02 + bb2, 0.f), fmaxf(c03 + bb3, 0.f));
    if (g0 + 1 < n) *(float4*)&x1out[(size_t)(g0 + 1) * 128 + j0] = make_float4(
        fmaxf(c10 + bb0, 0.f), fmaxf(c11 + bb1, 0.f), fmaxf(c12 + bb2, 0.f), fmaxf(c13 + bb3, 0.f));
    if (g0 + 2 < n) *(float4*)&x1out[(size_t)(g0 + 2) * 128 + j0] = make_float4(
        fmaxf(c20 + bb0, 0.f), fmaxf(c21 + bb1, 0.f), fmaxf(c22 + bb2, 0.f), fmaxf(c23 + bb3, 0.f));
    if (g0 + 3 < n) *(float4*)&x1out[(size_t)(g0 + 3) * 128 + j0] = make_float4(
        fmaxf(c30 + bb0, 0.f), fmaxf(c31 + bb1, 0.f), fmaxf(c32 + bb2, 0.f), fmaxf(c33 + bb3, 0.f));
}

// ---------------- gemm2: h2h = (half)(x1 @ W2); 512 thr, 128-row block, 4x4/thread ----------------
// LDS: W2 32KB + xl[128][132] 66KB (pad +4 -> row-reads conflict-free) = 98KB -> 1 block/CU.

#define XL2_LD 132

__global__ __launch_bounds__(512) void gemm2_kernel(
    const float* __restrict__ x1, const float* __restrict__ W2,
    __half* __restrict__ h2h, int n)
{
    __shared__ float Wl[128 * 64];        // 32 KB
    __shared__ float xl[128 * XL2_LD];    // 66 KB (padded rows)
    const int tid = threadIdx.x;

    // stage W2: 2048 float4, 4 per thread
    {
        const float4* W4 = (const float4*)W2;
        float4* Wl4 = (float4*)Wl;
        #pragma unroll
        for (int i = 0; i < 4; ++i) Wl4[tid + i * 512] = W4[tid + i * 512];
    }

    const int row0 = blockIdx.x * 128;
    // stage 128 rows of x1: 4096 float4, 8 per thread
    #pragma unroll
    for (int t = 0; t < 8; ++t) {
        const int idx = tid + t * 512;
        const int rr = idx >> 5;
        const int c4 = idx & 31;
        const int grow = row0 + rr;
        float4 v = make_float4(0.f, 0.f, 0.f, 0.f);
        if (grow < n) v = *(const float4*)&x1[(size_t)grow * 128 + c4 * 4];
        *(float4*)&xl[rr * XL2_LD + c4 * 4] = v;
    }
    __syncthreads();

    const int colg = tid & 15;        // 16 col groups x 4 cols = 64 cols
    const int j0   = colg * 4;
    const int r0   = (tid >> 4) * 4;  // 32 row groups x 4 rows = 128 rows

    float c00 = 0.f, c01 = 0.f, c02 = 0.f, c03 = 0.f;
    float c10 = 0.f, c11 = 0.f, c12 = 0.f, c13 = 0.f;
    float c20 = 0.f, c21 = 0.f, c22 = 0.f, c23 = 0.f;
    float c30 = 0.f, c31 = 0.f, c32 = 0.f, c33 = 0.f;
    #pragma unroll 8
    for (int k = 0; k < 128; ++k) {
        const float4 w = *(const float4*)&Wl[k * 64 + j0];
        const float x0 = xl[(r0 + 0) * XL2_LD + k];
        const float x1v = xl[(r0 + 1) * XL2_LD + k];
        const float x2 = xl[(r0 + 2) * XL2_LD + k];
        const float x3 = xl[(r0 + 3) * XL2_LD + k];
        c00 = fmaf(x0, w.x, c00);  c01 = fmaf(x0, w.y, c01);
        c02 = fmaf(x0, w.z, c02);  c03 = fmaf(x0, w.w, c03);
        c10 = fmaf(x1v, w.x, c10); c11 = fmaf(x1v, w.y, c11);
        c12 = fmaf(x1v, w.z, c12); c13 = fmaf(x1v, w.w, c13);
        c20 = fmaf(x2, w.x, c20);  c21 = fmaf(x2, w.y, c21);
        c22 = fmaf(x2, w.z, c22);  c23 = fmaf(x2, w.w, c23);
        c30 = fmaf(x3, w.x, c30);  c31 = fmaf(x3, w.y, c31);
        c32 = fmaf(x3, w.z, c32);  c33 = fmaf(x3, w.w, c33);
    }
    const int g0 = row0 + r0;
    if (g0 + 0 < n) {
        union { __half2 h[2]; float2 f; } u;
        u.h[0] = __floats2half2_rn(c00, c01);
        u.h[1] = __floats2half2_rn(c02, c03);
        *(float2*)&h2h[(size_t)(g0 + 0) * 64 + j0] = u.f;
    }
    if (g0 + 1 < n) {
        union { __half2 h[2]; float2 f; } u;
        u.h[0] = __floats2half2_rn(c10, c11);
        u.h[1] = __floats2half2_rn(c12, c13);
        *(float2*)&h2h[(size_t)(g0 + 1) * 64 + j0] = u.f;
    }
    if (g0 + 2 < n) {
        union { __half2 h[2]; float2 f; } u;
        u.h[0] = __floats2half2_rn(c20, c21);
        u.h[1] = __floats2half2_rn(c22, c23);
        *(float2*)&h2h[(size_t)(g0 + 2) * 64 + j0] = u.f;
    }
    if (g0 + 3 < n) {
        union { __half2 h[2]; float2 f; } u;
        u.h[0] = __floats2half2_rn(c30, c31);
        u.h[1] = __floats2half2_rn(c32, c33);
        *(float2*)&h2h[(size_t)(g0 + 3) * 64 + j0] = u.f;
    }
}

// ---------------- gather2 + bias + softmax: out[d] = softmax(Agg(h2h)[d] + b2), F=64, 8x unroll ----------------

__global__ __launch_bounds__(256) void gather2_softmax_kernel(
    const __half* __restrict__ h2h, const int* __restrict__ rowptr,
    const int* __restrict__ col, const float* __restrict__ dinv,
    const float* __restrict__ b2, float* __restrict__ out, int n)
{
    const int wid = blockIdx.x * 4 + (threadIdx.x >> 6);
    if (wid >= n) return;
    const int lane = threadIdx.x & 63;
    const float bias = b2[lane];
    const float dd = dinv[wid];
    float a0 = __half2float(h2h[(size_t)wid * 64 + lane]) * dd * dd;
    float a1 = 0.f, a2 = 0.f, a3 = 0.f;
    const int jb = rowptr[wid];
    const int je = rowptr[wid + 1];
    int j = jb;
    // 8-way unroll: 8 independent row gathers in flight per iteration
    for (; j + 7 < je; j += 8) {
        const int s0 = col[j + 0];
        const int s1 = col[j + 1];
        const int s2 = col[j + 2];
        const int s3 = col[j + 3];
        const int s4 = col[j + 4];
        const int s5 = col[j + 5];
        const int s6 = col[j + 6];
        const int s7 = col[j + 7];
        const float n0 = dinv[s0] * dd;
        const float n1 = dinv[s1] * dd;
        const float n2 = dinv[s2] * dd;
        const float n3 = dinv[s3] * dd;
        const float n4 = dinv[s4] * dd;
        const float n5 = dinv[s5] * dd;
        const float n6 = dinv[s6] * dd;
        const float n7 = dinv[s7] * dd;
        const float v0 = __half2float(h2h[(size_t)s0 * 64 + lane]);
        const float v1 = __half2float(h2h[(size_t)s1 * 64 + lane]);
        const float v2 = __half2float(h2h[(size_t)s2 * 64 + lane]);
        const float v3 = __half2float(h2h[(size_t)s3 * 64 + lane]);
        const float v4 = __half2float(h2h[(size_t)s4 * 64 + lane]);
        const float v5 = __half2float(h2h[(size_t)s5 * 64 + lane]);
        const float v6 = __half2float(h2h[(size_t)s6 * 64 + lane]);
        const float v7 = __half2float(h2h[(size_t)s7 * 64 + lane]);
        a0 = fmaf(v0, n0, a0);
        a1 = fmaf(v1, n1, a1);
        a2 = fmaf(v2, n2, a2);
        a3 = fmaf(v3, n3, a3);
        a0 = fmaf(v4, n4, a0);
        a1 = fmaf(v5, n5, a1);
        a2 = fmaf(v6, n6, a2);
        a3 = fmaf(v7, n7, a3);
    }
    for (; j < je; ++j) {
        const int s = col[j];
        a0 = fmaf(__half2float(h2h[(size_t)s * 64 + lane]), dinv[s] * dd, a0);
    }
    float acc = (a0 + a1) + (a2 + a3);
    acc += bias;

    float m = acc;
    #pragma unroll
    for (int off = 32; off > 0; off >>= 1) m = fmaxf(m, __shfl_xor(m, off));
    const float ev = expf(acc - m);
    float ssum = ev;
    #pragma unroll
    for (int off = 32; off > 0; off >>= 1) ssum += __shfl_xor(ssum, off);
    out[(size_t)wid * 64 + lane] = ev / ssum;
}

// ---------------- launch ----------------

extern "C" void kernel_launch(void* const* d_in, const int* in_sizes, int n_in,
                              void* d_out, int out_size, void* d_ws, size_t ws_size,
                              hipStream_t stream)
{
    const float* x   = (const float*)d_in[0];
    const int*   ei  = (const int*)d_in[1];
    const float* W1  = (const float*)d_in[2];
    const float* b1  = (const float*)d_in[3];
    const float* W2  = (const float*)d_in[4];
    const float* b2  = (const float*)d_in[5];

    const int n = in_sizes[0] / 128;
    const int E = in_sizes[1] / 2;
    const int* src = ei;
    const int* dst = ei + E;

    // workspace layout (~49 MB total, 16B-aligned where vector-accessed)
    float* ws    = (float*)d_ws;
    float* dinv  = ws;                             // n floats
    float* z1    = dinv + n;                       // n*128 floats (z1, then x1 in-place)
    __half* xh   = (__half*)(z1 + (size_t)n * 128);// n*128 halfs
    __half* h2h  = xh + (size_t)n * 128;           // n*64 halfs
    int* count   = (int*)(h2h + (size_t)n * 64);   // n
    int* rowptr  = count + n;                      // n+1
    int* cursor  = rowptr + (n + 1);               // n
    int* bsum    = cursor + n;                     // 256
    int* boff    = bsum + 256;                     // 256
    int* col     = boff + 256;                     // E

    const int B = 256;
    const int nb = (n + SCAN_B - 1) / SCAN_B;  // 196 for n=50000 (must be <= 256)

    // x -> relu -> fp16 staging (n*128 elems, 8 per thread)
    relu_half_kernel<<<((n * 16) + B - 1) / B, B, 0, stream>>>(x, xh, n * 16);

    // CSR build + dinv
    zero_count_kernel<<<(n + B - 1) / B, B, 0, stream>>>(count, n);
    count_kernel<<<(E + B - 1) / B, B, 0, stream>>>(dst, count, E);
    scanA_kernel<<<nb, SCAN_B, 0, stream>>>(count, rowptr, bsum, n);
    scanB_kernel<<<1, SCAN_B, 0, stream>>>(bsum, boff, nb);
    scanC_kernel<<<(n + B - 1) / B, B, 0, stream>>>(rowptr, boff, count, cursor, dinv, n, E);
    fill_kernel<<<(E + B - 1) / B, B, 0, stream>>>(src, dst, cursor, col, E);

    // layer 1: aggregate relu(x) (fp16 staged), then GEMM (+b1, relu) in-place
    const int gather_blocks = (n + 3) / 4;     // 4 waves (nodes) per block
    gather1_kernel<<<gather_blocks, B, 0, stream>>>(xh, rowptr, col, dinv, z1, n);

    gemm1_kernel<<<(n + 63) / 64, 512, 0, stream>>>(z1, W1, b1, z1, n);

    // layer 2: GEMM -> fp16, then aggregate + bias + softmax fused
    gemm2_kernel<<<(n + 127) / 128, 512, 0, stream>>>(z1, W2, h2h, n);
    gather2_softmax_kernel<<<gather_blocks, B, 0, stream>>>(h2h, rowptr, col, dinv, b2,
                                                            (float*)d_out, n);
}